// Round 1
// baseline (1793.525 us; speedup 1.0000x reference)
//
#include <hip/hip_runtime.h>
#include <hip/hip_bf16.h>

#define GG 128   // graphs total (2 branches x 64)
#define LLN 128  // nodes per graph
#define DDIM 300
#define NH 4

typedef float4 f4;

__device__ __forceinline__ float wsum(float v) {
  #pragma unroll
  for (int o = 32; o > 0; o >>= 1) v += __shfl_xor(v, o, 64);
  return v;
}
__device__ __forceinline__ float wmax(float v) {
  #pragma unroll
  for (int o = 32; o > 0; o >>= 1) v = fmaxf(v, __shfl_xor(v, o, 64));
  return v;
}
__device__ __forceinline__ float dot4(f4 a, f4 b) {
  return a.x*b.x + a.y*b.y + a.z*b.z + a.w*b.w;
}
__device__ __forceinline__ f4 add4(f4 a, f4 b) {
  return make_float4(a.x+b.x, a.y+b.y, a.z+b.z, a.w+b.w);
}
__device__ __forceinline__ f4 scale4(f4 a, float s) {
  return make_float4(a.x*s, a.y*s, a.z*s, a.w*s);
}
#define FMA4(acc, v, s) { (acc).x += (s)*(v).x; (acc).y += (s)*(v).y; (acc).z += (s)*(v).z; (acc).w += (s)*(v).w; }

// ---------------- embedding gather: h[g][l][d] = emb[sent[l][b]][d]
__global__ __launch_bounds__(256) void gather_kernel(
    const float* __restrict__ emb, const int* __restrict__ s1,
    const int* __restrict__ s2, float* __restrict__ h) {
  int gl = blockIdx.x;
  int g = gl >> 7, l = gl & 127;
  const int* s = (g >= 64) ? s2 : s1;
  int tok = s[l * 64 + (g & 63)];
  const float* src = emb + (size_t)tok * DDIM;
  float* dst = h + (size_t)gl * DDIM;
  for (int d = threadIdx.x; d < DDIM; d += 256) dst[d] = src[d];
}

// ---------------- Vt[g][k][l] = relu(h[g][l][k] * w[k])  (transposed V)
__global__ __launch_bounds__(256) void vt_kernel(
    const float* __restrict__ h, const float* __restrict__ w, float* __restrict__ Vt) {
  __shared__ float st[32][65];
  int kt = blockIdx.x, lt = blockIdx.y, g = blockIdx.z;
  int k0 = kt * 32, l0 = lt * 64;
  int tid = threadIdx.x;
  for (int idx = tid; idx < 64 * 32; idx += 256) {
    int ll = idx >> 5, kk = idx & 31;
    int k = k0 + kk;
    float v = 0.f;
    if (k < DDIM) v = fmaxf(h[((size_t)g * LLN + l0 + ll) * DDIM + k] * w[k], 0.f);
    st[kk][ll] = v;
  }
  __syncthreads();
  for (int idx = tid; idx < 64 * 32; idx += 256) {
    int kk = idx >> 6, l = idx & 63;
    int k = k0 + kk;
    if (k < DDIM) Vt[((size_t)g * DDIM + k) * LLN + l0 + l] = st[kk][l];
  }
}

// ---------------- adjacency: A[g][i][j] = (dot(Vi,Vj) >= 0.1 || i==j) ? 1 : 0
// block = (i-tile of 32, g); wave ii owns 8 i-rows; lanes cover j (2 chunks of 64)
__global__ __launch_bounds__(256) void adj_kernel(
    const float* __restrict__ h, const float* __restrict__ w,
    const float* __restrict__ Vt, float* __restrict__ A) {
  __shared__ float vit[DDIM][36];
  int i0 = blockIdx.x * 32, g = blockIdx.y;
  int tid = threadIdx.x;
  for (int idx = tid; idx < 32 * DDIM; idx += 256) {
    int i = idx / DDIM, k = idx - i * DDIM;
    vit[k][i] = fmaxf(h[((size_t)g * LLN + i0 + i) * DDIM + k] * w[k], 0.f);
  }
  __syncthreads();
  int ii = tid >> 6, lane = tid & 63;
  float acc0[8], acc1[8];
  #pragma unroll
  for (int m = 0; m < 8; ++m) { acc0[m] = 0.f; acc1[m] = 0.f; }
  const float* vtg = Vt + (size_t)g * DDIM * LLN;
  for (int k = 0; k < DDIM; ++k) {
    f4 alo = *(const f4*)&vit[k][ii * 8];
    f4 ahi = *(const f4*)&vit[k][ii * 8 + 4];
    float vj0 = vtg[k * LLN + lane];
    float vj1 = vtg[k * LLN + 64 + lane];
    acc0[0] += alo.x * vj0; acc0[1] += alo.y * vj0; acc0[2] += alo.z * vj0; acc0[3] += alo.w * vj0;
    acc0[4] += ahi.x * vj0; acc0[5] += ahi.y * vj0; acc0[6] += ahi.z * vj0; acc0[7] += ahi.w * vj0;
    acc1[0] += alo.x * vj1; acc1[1] += alo.y * vj1; acc1[2] += alo.z * vj1; acc1[3] += alo.w * vj1;
    acc1[4] += ahi.x * vj1; acc1[5] += ahi.y * vj1; acc1[6] += ahi.z * vj1; acc1[7] += ahi.w * vj1;
  }
  float* Ag = A + ((size_t)g * LLN + i0 + ii * 8) * LLN;
  #pragma unroll
  for (int m = 0; m < 8; ++m) {
    int i = i0 + ii * 8 + m;
    Ag[m * LLN + lane]      = (acc0[m] >= 0.1f || i == lane)        ? 1.f : 0.f;
    Ag[m * LLN + 64 + lane] = (acc1[m] >= 0.1f || i == (64 + lane)) ? 1.f : 0.f;
  }
}

// ---------------- z = h @ gatW   [16384,300]x[300,1200]
__global__ __launch_bounds__(256) void zmm_kernel(
    const float* __restrict__ Aq, const float* __restrict__ Bw, float* __restrict__ C) {
  __shared__ float As[32][128];
  __shared__ float Bs[32][128];
  int n0 = blockIdx.x * 128, m0 = blockIdx.y * 128;
  int tid = threadIdx.x;
  int tyy = tid >> 4, txx = tid & 15;
  float acc[8][8];
  #pragma unroll
  for (int a = 0; a < 8; ++a)
    #pragma unroll
    for (int b = 0; b < 8; ++b) acc[a][b] = 0.f;

  for (int kc = 0; kc < 300; kc += 32) {
    #pragma unroll
    for (int q = 0; q < 4; ++q) {
      int idx = tid + q * 256;
      int row = idx >> 3, kq = idx & 7;
      int k = kc + kq * 4;
      f4 v = make_float4(0.f, 0.f, 0.f, 0.f);
      if (k + 3 < 300) v = *(const f4*)(Aq + (size_t)(m0 + row) * 300 + k);
      As[kq*4+0][row] = v.x; As[kq*4+1][row] = v.y;
      As[kq*4+2][row] = v.z; As[kq*4+3][row] = v.w;
    }
    #pragma unroll
    for (int q = 0; q < 4; ++q) {
      int idx = tid + q * 256;
      int kk = idx >> 5, j4 = idx & 31;
      int k = kc + kk, col = n0 + j4 * 4;
      f4 v = make_float4(0.f, 0.f, 0.f, 0.f);
      if (k < 300 && col < 1200) v = *(const f4*)(Bw + (size_t)k * 1200 + col);
      int slot = ((j4 & 1) << 4) | (j4 >> 1);
      *(f4*)&Bs[kk][slot * 4] = v;
    }
    __syncthreads();
    #pragma unroll
    for (int kk = 0; kk < 32; ++kk) {
      f4 a0 = *(const f4*)&As[kk][tyy * 8];
      f4 a1 = *(const f4*)&As[kk][tyy * 8 + 4];
      f4 b0 = *(const f4*)&Bs[kk][txx * 4];
      f4 b1 = *(const f4*)&Bs[kk][(16 + txx) * 4];
      float av[8] = {a0.x,a0.y,a0.z,a0.w,a1.x,a1.y,a1.z,a1.w};
      float bv[8] = {b0.x,b0.y,b0.z,b0.w,b1.x,b1.y,b1.z,b1.w};
      #pragma unroll
      for (int mi = 0; mi < 8; ++mi)
        #pragma unroll
        for (int nj = 0; nj < 8; ++nj) acc[mi][nj] += av[mi] * bv[nj];
    }
    __syncthreads();
  }
  #pragma unroll
  for (int mi = 0; mi < 8; ++mi) {
    int row = m0 + tyy * 8 + mi;
    int col = n0 + txx * 8;
    if (col < 1200) {
      *(f4*)(C + (size_t)row * 1200 + col)     = make_float4(acc[mi][0],acc[mi][1],acc[mi][2],acc[mi][3]);
      *(f4*)(C + (size_t)row * 1200 + col + 4) = make_float4(acc[mi][4],acc[mi][5],acc[mi][6],acc[mi][7]);
    }
  }
}

// ---------------- el/er: per-(g,l,h) dots of z row with attn vectors
__global__ __launch_bounds__(256) void elr_kernel(
    const float* __restrict__ z, const float* __restrict__ attn_l,
    const float* __restrict__ attn_r, float* __restrict__ el, float* __restrict__ er) {
  int tid = threadIdx.x, ii = tid >> 6, lane = tid & 63;
  int gl = blockIdx.x * 4 + ii;
  const float* zrow = z + (size_t)gl * 1200;
  #pragma unroll
  for (int h = 0; h < NH; ++h) {
    float pl = 0.f, pr = 0.f;
    for (int d = lane; d < DDIM; d += 64) {
      float zv = zrow[h * DDIM + d];
      pl += zv * attn_l[h * DDIM + d];
      pr += zv * attn_r[h * DDIM + d];
    }
    pl = wsum(pl); pr = wsum(pr);
    if (lane == 0) { el[(size_t)gl * NH + h] = pl; er[(size_t)gl * NH + h] = pr; }
  }
}

// ---------------- fused: neigh -> SAGE fc -> GAT softmax+agg -> head fusion -> residual
// block = (16-row tile, g); 4 waves; wave ii owns rows ii*4..+3; lanes cover d as f4 chunks {lane, lane+64} of 75
__global__ __launch_bounds__(256) void agg_kernel(
    const float* __restrict__ h_in,
    const float* __restrict__ Agat,
    const float* __restrict__ Asage,
    const float* __restrict__ z,
    const float* __restrict__ el,
    const float* __restrict__ er,
    const float* __restrict__ gat_b,
    const float* __restrict__ sageW,
    const float* __restrict__ sage_b,
    const float* __restrict__ headW,
    const float* __restrict__ head_b,
    float* __restrict__ h_out) {
  __shared__ float As[16][128];
  __shared__ float ns[16][304];
  __shared__ float at[128][20];

  int i0 = blockIdx.x * 16, g = blockIdx.y;
  int tid = threadIdx.x, ii = tid >> 6, lane = tid & 63;
  int dq0 = lane, dq1 = lane + 64;
  bool ok1 = dq1 < 75;
  const f4 zero4 = make_float4(0.f, 0.f, 0.f, 0.f);
  const f4* h4 = (const f4*)(h_in + (size_t)g * LLN * DDIM);   // row stride 75 f4

  // stage A_sage rows
  {
    const float* src = Asage + ((size_t)g * LLN + i0) * LLN;
    for (int idx = tid; idx < 16 * 128; idx += 256) As[idx >> 7][idx & 127] = src[idx];
  }
  __syncthreads();

  // deg^-1 per own row
  float dinv[4];
  #pragma unroll
  for (int r = 0; r < 4; ++r) {
    float s = As[ii * 4 + r][lane] + As[ii * 4 + r][64 + lane];
    s = wsum(s);
    dinv[r] = 1.f / (s + 1.f);
  }

  // neigh = (Asage @ h + h) * dinv  -> ns (own rows)
  f4 acc0[4], acc1[4];
  #pragma unroll
  for (int r = 0; r < 4; ++r) { acc0[r] = zero4; acc1[r] = zero4; }
  for (int j = 0; j < 128; ++j) {
    float a0 = As[ii*4+0][j], a1 = As[ii*4+1][j], a2 = As[ii*4+2][j], a3 = As[ii*4+3][j];
    f4 hv0 = h4[j * 75 + dq0];
    f4 hv1 = ok1 ? h4[j * 75 + dq1] : zero4;
    FMA4(acc0[0], hv0, a0); FMA4(acc0[1], hv0, a1); FMA4(acc0[2], hv0, a2); FMA4(acc0[3], hv0, a3);
    FMA4(acc1[0], hv1, a0); FMA4(acc1[1], hv1, a1); FMA4(acc1[2], hv1, a2); FMA4(acc1[3], hv1, a3);
  }
  #pragma unroll
  for (int r = 0; r < 4; ++r) {
    int i = i0 + ii * 4 + r;
    f4 hv0 = h4[i * 75 + dq0];
    f4 hv1 = ok1 ? h4[i * 75 + dq1] : zero4;
    f4 n0 = scale4(add4(acc0[r], hv0), dinv[r]);
    f4 n1 = scale4(add4(acc1[r], hv1), dinv[r]);
    *(f4*)&ns[ii*4+r][dq0 * 4] = n0;
    if (ok1) *(f4*)&ns[ii*4+r][dq1 * 4] = n1;
  }
  __syncthreads();

  // restage As with A_gat
  {
    const float* src = Agat + ((size_t)g * LLN + i0) * LLN;
    for (int idx = tid; idx < 16 * 128; idx += 256) As[idx >> 7][idx & 127] = src[idx];
  }
  __syncthreads();

  // SAGE head: hd = ns @ sageW + sage_b
  f4 hd0[4], hd1[4];
  #pragma unroll
  for (int r = 0; r < 4; ++r) { hd0[r] = zero4; hd1[r] = zero4; }
  const f4* sW4 = (const f4*)sageW;   // [300][75]
  for (int k = 0; k < DDIM; ++k) {
    float n0 = ns[ii*4+0][k], n1 = ns[ii*4+1][k], n2 = ns[ii*4+2][k], n3 = ns[ii*4+3][k];
    f4 w0 = sW4[k * 75 + dq0];
    f4 w1 = ok1 ? sW4[k * 75 + dq1] : zero4;
    FMA4(hd0[0], w0, n0); FMA4(hd0[1], w0, n1); FMA4(hd0[2], w0, n2); FMA4(hd0[3], w0, n3);
    FMA4(hd1[0], w1, n0); FMA4(hd1[1], w1, n1); FMA4(hd1[2], w1, n2); FMA4(hd1[3], w1, n3);
  }
  {
    const f4* sb4 = (const f4*)sage_b;
    f4 sb0 = sb4[dq0];
    f4 sb1 = ok1 ? sb4[dq1] : zero4;
    #pragma unroll
    for (int r = 0; r < 4; ++r) { hd0[r] = add4(hd0[r], sb0); hd1[r] = add4(hd1[r], sb1); }
  }

  f4 pw0 = ((const f4*)headW)[dq0];
  f4 pw1 = ok1 ? ((const f4*)headW)[dq1] : zero4;
  float hbias = head_b[0];

  f4 oacc0[4], oacc1[4];
  #pragma unroll
  for (int r = 0; r < 4; ++r) {
    float p = dot4(hd0[r], pw0) + dot4(hd1[r], pw1);
    p = wsum(p);
    float wgt = 1.f / (1.f + __expf(-(p + hbias)));
    oacc0[r] = scale4(hd0[r], wgt);
    oacc1[r] = scale4(hd1[r], wgt);
  }

  // GAT heads
  const f4* z4 = (const f4*)(z + (size_t)g * LLN * 1200);   // row stride 300 f4
  const f4* gb4 = (const f4*)gat_b;                          // [4][75]
  for (int h = 0; h < NH; ++h) {
    float elv0 = el[((size_t)g * LLN + lane) * NH + h];
    float elv1 = el[((size_t)g * LLN + 64 + lane) * NH + h];
    #pragma unroll
    for (int r = 0; r < 4; ++r) {
      int i = i0 + ii * 4 + r;
      float eri = er[((size_t)g * LLN + i) * NH + h];
      float m0 = As[ii*4+r][lane], m1 = As[ii*4+r][64 + lane];
      float e0 = eri + elv0; e0 = e0 >= 0.f ? e0 : 0.2f * e0;
      float e1 = eri + elv1; e1 = e1 >= 0.f ? e1 : 0.2f * e1;
      float x0 = m0 > 0.f ? e0 : -3.0e38f;
      float x1 = m1 > 0.f ? e1 : -3.0e38f;
      float mx = wmax(fmaxf(x0, x1));
      float p0 = m0 > 0.f ? __expf(e0 - mx) : 0.f;
      float p1 = m1 > 0.f ? __expf(e1 - mx) : 0.f;
      float s = wsum(p0 + p1);
      float inv = 1.f / s;
      at[lane][ii*4+r] = p0 * inv;
      at[64 + lane][ii*4+r] = p1 * inv;
    }
    __builtin_amdgcn_wave_barrier();   // same-wave LDS write->read ordering (compiler fence)

    #pragma unroll
    for (int r = 0; r < 4; ++r) { hd0[r] = zero4; hd1[r] = zero4; }
    int hb75 = h * 75;
    for (int j = 0; j < 128; ++j) {
      f4 al = *(const f4*)&at[j][ii * 4];
      f4 zv0 = z4[j * 300 + hb75 + dq0];
      f4 zv1 = ok1 ? z4[j * 300 + hb75 + dq1] : zero4;
      FMA4(hd0[0], zv0, al.x); FMA4(hd0[1], zv0, al.y); FMA4(hd0[2], zv0, al.z); FMA4(hd0[3], zv0, al.w);
      FMA4(hd1[0], zv1, al.x); FMA4(hd1[1], zv1, al.y); FMA4(hd1[2], zv1, al.z); FMA4(hd1[3], zv1, al.w);
    }
    {
      f4 gb0 = gb4[hb75 + dq0];
      f4 gb1 = ok1 ? gb4[hb75 + dq1] : zero4;
      #pragma unroll
      for (int r = 0; r < 4; ++r) { hd0[r] = add4(hd0[r], gb0); hd1[r] = add4(hd1[r], gb1); }
    }
    #pragma unroll
    for (int r = 0; r < 4; ++r) {
      float p = dot4(hd0[r], pw0) + dot4(hd1[r], pw1);
      p = wsum(p);
      float wgt = 1.f / (1.f + __expf(-(p + hbias)));
      FMA4(oacc0[r], hd0[r], wgt);
      FMA4(oacc1[r], hd1[r], wgt);
    }
    __builtin_amdgcn_wave_barrier();
  }

  // residual write
  f4* ho4 = (f4*)(h_out + (size_t)g * LLN * DDIM);
  #pragma unroll
  for (int r = 0; r < 4; ++r) {
    int i = i0 + ii * 4 + r;
    f4 hv0 = h4[i * 75 + dq0];
    ho4[i * 75 + dq0] = add4(hv0, oacc0[r]);
    if (ok1) {
      f4 hv1 = h4[i * 75 + dq1];
      ho4[i * 75 + dq1] = add4(hv1, oacc1[r]);
    }
  }
}

// ---------------- WeightAndSum pool per graph
__global__ __launch_bounds__(256) void pool_kernel(
    const float* __restrict__ h, const float* __restrict__ poolW,
    const float* __restrict__ pool_b, float* __restrict__ gvec) {
  __shared__ float ws_[128];
  int g = blockIdx.x, tid = threadIdx.x, ii = tid >> 6, lane = tid & 63;
  const float* hg = h + (size_t)g * LLN * DDIM;
  float pb = pool_b[0];
  for (int m = 0; m < 32; ++m) {
    int l = ii * 32 + m;
    float p = 0.f;
    for (int d = lane; d < DDIM; d += 64) p += hg[l * DDIM + d] * poolW[d];
    p = wsum(p);
    if (lane == 0) ws_[l] = 1.f / (1.f + __expf(-(p + pb)));
  }
  __syncthreads();
  for (int d = tid; d < DDIM; d += 256) {
    float acc = 0.f;
    for (int l = 0; l < 128; ++l) acc += hg[l * DDIM + d] * ws_[l];
    gvec[(size_t)g * DDIM + d] = acc;
  }
}

// ---------------- pearson over pairs
__global__ __launch_bounds__(64) void pearson_kernel(
    const float* __restrict__ gvec, float* __restrict__ out) {
  int b = blockIdx.x, lane = threadIdx.x;
  const float* g1 = gvec + (size_t)b * DDIM;
  const float* g2 = gvec + (size_t)(64 + b) * DDIM;
  float v1[5], v2[5];
  float s1 = 0.f, s2 = 0.f;
  #pragma unroll
  for (int q = 0; q < 5; ++q) {
    int d = lane + 64 * q;
    v1[q] = (d < DDIM) ? g1[d] : 0.f;
    v2[q] = (d < DDIM) ? g2[d] : 0.f;
    s1 += v1[q]; s2 += v2[q];
  }
  s1 = wsum(s1); s2 = wsum(s2);
  float m1 = s1 / 300.f, m2 = s2 / 300.f;
  float a = 0.f, bb = 0.f, c = 0.f;
  #pragma unroll
  for (int q = 0; q < 5; ++q) {
    int d = lane + 64 * q;
    if (d < DDIM) {
      float x = v1[q] - m1, y = v2[q] - m2;
      a += x * y; bb += x * x; c += y * y;
    }
  }
  a = wsum(a); bb = wsum(bb); c = wsum(c);
  if (lane == 0) out[b] = 5.f * a / (sqrtf(bb) * sqrtf(c));
}

extern "C" void kernel_launch(void* const* d_in, const int* in_sizes, int n_in,
                              void* d_out, int out_size, void* d_ws, size_t ws_size,
                              hipStream_t stream) {
  (void)in_sizes; (void)n_in; (void)out_size; (void)ws_size;
  const float* emb   = (const float*)d_in[0];
  const float* simw1 = (const float*)d_in[1];
  const float* simw2 = (const float*)d_in[2];
  const float* LP[2][8];
  for (int l = 0; l < 2; ++l)
    for (int p = 0; p < 8; ++p) LP[l][p] = (const float*)d_in[3 + l * 8 + p];
  const float* poolW  = (const float*)d_in[19];
  const float* pool_b = (const float*)d_in[20];
  const int* s1 = (const int*)d_in[21];
  const int* s2 = (const int*)d_in[22];
  float* out = (float*)d_out;

  char* ws = (char*)d_ws;
  float* hA   = (float*)(ws + 0);           // 19,660,800 B
  float* hB   = (float*)(ws + 19660800);    // 19,660,800 B
  float* Agat = (float*)(ws + 39321600);    // 8,388,608 B
  float* Asag = (float*)(ws + 47710208);    // 8,388,608 B
  float* zb   = (float*)(ws + 56098816);    // 78,643,200 B
  float* elb  = (float*)(ws + 134742016);   // 262,144 B
  float* erb  = (float*)(ws + 135004160);   // 262,144 B
  float* gv   = (float*)(ws + 135266304);   // 153,600 B  (total 135,419,904)

  gather_kernel<<<GG * LLN, 256, 0, stream>>>(emb, s1, s2, hA);

  float* hin = hA; float* hout = hB;
  for (int l = 0; l < 2; ++l) {
    float* vt = hout;   // scratch: overwritten later by agg anyway
    vt_kernel<<<dim3(10, 2, GG), 256, 0, stream>>>(hin, simw2, vt);
    adj_kernel<<<dim3(4, GG), 256, 0, stream>>>(hin, simw2, vt, Agat);
    vt_kernel<<<dim3(10, 2, GG), 256, 0, stream>>>(hin, simw1, vt);
    adj_kernel<<<dim3(4, GG), 256, 0, stream>>>(hin, simw1, vt, Asag);
    zmm_kernel<<<dim3(10, 128), 256, 0, stream>>>(hin, LP[l][0], zb);
    elr_kernel<<<4096, 256, 0, stream>>>(zb, LP[l][1], LP[l][2], elb, erb);
    agg_kernel<<<dim3(8, GG), 256, 0, stream>>>(hin, Agat, Asag, zb, elb, erb,
        LP[l][3], LP[l][4], LP[l][5], LP[l][6], LP[l][7], hout);
    float* t = hin; hin = hout; hout = t;
  }

  pool_kernel<<<GG, 256, 0, stream>>>(hin, poolW, pool_b, gv);
  pearson_kernel<<<64, 64, 0, stream>>>(gv, out);
}

// Round 3
// 986.066 us; speedup vs baseline: 1.8189x; 1.8189x over previous
//
#include <hip/hip_runtime.h>
#include <hip/hip_bf16.h>

#define GG 128   // graphs total (2 branches x 64)
#define LLN 128
#define DDIM 300
#define NH 4

typedef float4 f4;
typedef __attribute__((ext_vector_type(4))) float f32x4;
typedef __attribute__((ext_vector_type(8))) short s16x8;

__device__ __forceinline__ float wsum(float v) {
  #pragma unroll
  for (int o = 32; o > 0; o >>= 1) v += __shfl_xor(v, o, 64);
  return v;
}
__device__ __forceinline__ float wmax(float v) {
  #pragma unroll
  for (int o = 32; o > 0; o >>= 1) v = fmaxf(v, __shfl_xor(v, o, 64));
  return v;
}
__device__ __forceinline__ f4 add4(f4 a, f4 b) {
  return make_float4(a.x+b.x, a.y+b.y, a.z+b.z, a.w+b.w);
}
__device__ __forceinline__ f4 scale4(f4 a, float s) {
  return make_float4(a.x*s, a.y*s, a.z*s, a.w*s);
}
#define FMA4(acc, v, s) { (acc).x += (s)*(v).x; (acc).y += (s)*(v).y; (acc).z += (s)*(v).z; (acc).w += (s)*(v).w; }

__device__ __forceinline__ unsigned short f2bf(float x) {
  unsigned int u = __float_as_uint(x);
  return (unsigned short)((u + 0x7fffu + ((u >> 16) & 1u)) >> 16);
}
__device__ __forceinline__ float bf2f(unsigned short b) {
  return __uint_as_float(((unsigned int)b) << 16);
}
__device__ __forceinline__ int swzq(int row, int q) { return q ^ ((row >> 1) & 3); }
__device__ __forceinline__ float sigm(float x) { return 1.f / (1.f + __expf(-x)); }

__device__ __forceinline__ f32x4 mfma3(s16x8 ah, s16x8 al, s16x8 bh, s16x8 bl, f32x4 c) {
  c = __builtin_amdgcn_mfma_f32_16x16x32_bf16(ah, bh, c, 0, 0, 0);
  c = __builtin_amdgcn_mfma_f32_16x16x32_bf16(ah, bl, c, 0, 0, 0);
  c = __builtin_amdgcn_mfma_f32_16x16x32_bf16(al, bh, c, 0, 0, 0);
  return c;
}

// ---------------- embedding gather
__global__ __launch_bounds__(256) void gather_kernel(
    const float* __restrict__ emb, const int* __restrict__ s1,
    const int* __restrict__ s2, float* __restrict__ h) {
  int gl = blockIdx.x;
  int g = gl >> 7, l = gl & 127;
  const int* s = (g >= 64) ? s2 : s1;
  int tok = s[l * 64 + (g & 63)];
  const float* src = emb + (size_t)tok * DDIM;
  float* dst = h + (size_t)gl * DDIM;
  for (int d = threadIdx.x; d < DDIM; d += 256) dst[d] = src[d];
}

// ---------------- Vt[g][k][l] = relu(h[g][l][k] * w[k])
__global__ __launch_bounds__(256) void vt_kernel(
    const float* __restrict__ h, const float* __restrict__ w, float* __restrict__ Vt) {
  __shared__ float st[32][65];
  int kt = blockIdx.x, lt = blockIdx.y, g = blockIdx.z;
  int k0 = kt * 32, l0 = lt * 64;
  int tid = threadIdx.x;
  for (int idx = tid; idx < 64 * 32; idx += 256) {
    int ll = idx >> 5, kk = idx & 31;
    int k = k0 + kk;
    float v = 0.f;
    if (k < DDIM) v = fmaxf(h[((size_t)g * LLN + l0 + ll) * DDIM + k] * w[k], 0.f);
    st[kk][ll] = v;
  }
  __syncthreads();
  for (int idx = tid; idx < 64 * 32; idx += 256) {
    int kk = idx >> 6, l = idx & 63;
    int k = k0 + kk;
    if (k < DDIM) Vt[((size_t)g * DDIM + k) * LLN + l0 + l] = st[kk][l];
  }
}

// ---------------- adjacency -> u8
__global__ __launch_bounds__(256) void adj_kernel(
    const float* __restrict__ h, const float* __restrict__ w,
    const float* __restrict__ Vt, unsigned char* __restrict__ A) {
  __shared__ float vit[DDIM][36];
  int i0 = blockIdx.x * 32, g = blockIdx.y;
  int tid = threadIdx.x;
  for (int idx = tid; idx < 32 * DDIM; idx += 256) {
    int i = idx / DDIM, k = idx - i * DDIM;
    vit[k][i] = fmaxf(h[((size_t)g * LLN + i0 + i) * DDIM + k] * w[k], 0.f);
  }
  __syncthreads();
  int ii = tid >> 6, lane = tid & 63;
  float acc0[8], acc1[8];
  #pragma unroll
  for (int m = 0; m < 8; ++m) { acc0[m] = 0.f; acc1[m] = 0.f; }
  const float* vtg = Vt + (size_t)g * DDIM * LLN;
  for (int k = 0; k < DDIM; ++k) {
    f4 alo = *(const f4*)&vit[k][ii * 8];
    f4 ahi = *(const f4*)&vit[k][ii * 8 + 4];
    float vj0 = vtg[k * LLN + lane];
    float vj1 = vtg[k * LLN + 64 + lane];
    acc0[0] += alo.x * vj0; acc0[1] += alo.y * vj0; acc0[2] += alo.z * vj0; acc0[3] += alo.w * vj0;
    acc0[4] += ahi.x * vj0; acc0[5] += ahi.y * vj0; acc0[6] += ahi.z * vj0; acc0[7] += ahi.w * vj0;
    acc1[0] += alo.x * vj1; acc1[1] += alo.y * vj1; acc1[2] += alo.z * vj1; acc1[3] += alo.w * vj1;
    acc1[4] += ahi.x * vj1; acc1[5] += ahi.y * vj1; acc1[6] += ahi.z * vj1; acc1[7] += ahi.w * vj1;
  }
  unsigned char* Ag = A + ((size_t)g * LLN + i0 + ii * 8) * LLN;
  #pragma unroll
  for (int m = 0; m < 8; ++m) {
    int i = i0 + ii * 8 + m;
    Ag[m * LLN + lane]      = (acc0[m] >= 0.1f || i == lane)        ? 1 : 0;
    Ag[m * LLN + 64 + lane] = (acc1[m] >= 0.1f || i == (64 + lane)) ? 1 : 0;
  }
}

// ---------------- prepW: transpose+split weights into bf16 hi/lo, padded
// gWT [1280][320], sWT [320][320]
__global__ __launch_bounds__(256) void prepw_kernel(
    const float* __restrict__ gatW, const float* __restrict__ sageW,
    unsigned short* __restrict__ gWTh, unsigned short* __restrict__ gWTl,
    unsigned short* __restrict__ sWTh, unsigned short* __restrict__ sWTl) {
  int idx = blockIdx.x * 256 + threadIdx.x;
  if (idx < 1280 * 320) {
    int n = idx / 320, k = idx % 320;
    float v = (n < 1200 && k < 300) ? gatW[(size_t)k * 1200 + n] : 0.f;
    unsigned short hv = f2bf(v);
    gWTh[idx] = hv;
    gWTl[idx] = f2bf(v - bf2f(hv));
  } else if (idx < 1280 * 320 + 320 * 320) {
    int i2 = idx - 1280 * 320;
    int n = i2 / 320, k = i2 % 320;
    float v = (n < 300 && k < 300) ? sageW[(size_t)k * 300 + n] : 0.f;
    unsigned short hv = f2bf(v);
    sWTh[i2] = hv;
    sWTl[i2] = f2bf(v - bf2f(hv));
  }
}

// ---------------- zmm: z = h @ gatW  via split-bf16 MFMA; writes zT hi/lo
// zT layout: [(g*4+head)*300 + d][128 j]
__global__ __launch_bounds__(256) void zmm_mfma(
    const float* __restrict__ h,
    const unsigned short* __restrict__ gWTh, const unsigned short* __restrict__ gWTl,
    unsigned short* __restrict__ zTh, unsigned short* __restrict__ zTl) {
  __shared__ __align__(16) unsigned short Ah[128 * 32], Al[128 * 32];
  __shared__ __align__(16) unsigned short Bh[128 * 32], Bl[128 * 32];
  int nt = blockIdx.x, n0 = nt * 128, m0 = blockIdx.y * 128;
  int tid = threadIdx.x, w = tid >> 6, lane = tid & 63;
  int lq = lane >> 4, lr = lane & 15, wr = w >> 1, wc = w & 1;
  f32x4 acc[4][4];
  #pragma unroll
  for (int a = 0; a < 4; ++a)
    #pragma unroll
    for (int b = 0; b < 4; ++b) acc[a][b] = (f32x4){0.f, 0.f, 0.f, 0.f};

  for (int kc = 0; kc < 10; ++kc) {
    // A stage (split from fp32 h): thread -> (row m, half)
    {
      int m = tid >> 1, half = tid & 1;
      const float* hp = h + (size_t)(m0 + m) * 300;
      int kb = kc * 32 + half * 16;
      float v[16];
      if (kb + 15 < 300) {
        f4 x0 = *(const f4*)(hp + kb);
        f4 x1 = *(const f4*)(hp + kb + 4);
        f4 x2 = *(const f4*)(hp + kb + 8);
        f4 x3 = *(const f4*)(hp + kb + 12);
        v[0]=x0.x; v[1]=x0.y; v[2]=x0.z; v[3]=x0.w;
        v[4]=x1.x; v[5]=x1.y; v[6]=x1.z; v[7]=x1.w;
        v[8]=x2.x; v[9]=x2.y; v[10]=x2.z; v[11]=x2.w;
        v[12]=x3.x; v[13]=x3.y; v[14]=x3.z; v[15]=x3.w;
      } else {
        #pragma unroll
        for (int e = 0; e < 16; ++e) { int k = kb + e; v[e] = (k < 300) ? hp[k] : 0.f; }
      }
      #pragma unroll
      for (int g4 = 0; g4 < 4; ++g4) {
        int klocal = half * 16 + g4 * 4;
        int q = klocal >> 3, wb = klocal & 7;
        int idx = m * 32 + swzq(m, q) * 8 + wb;
        ushort4 hv, lv;
        hv.x = f2bf(v[g4*4+0]); lv.x = f2bf(v[g4*4+0] - bf2f(hv.x));
        hv.y = f2bf(v[g4*4+1]); lv.y = f2bf(v[g4*4+1] - bf2f(hv.y));
        hv.z = f2bf(v[g4*4+2]); lv.z = f2bf(v[g4*4+2] - bf2f(hv.z));
        hv.w = f2bf(v[g4*4+3]); lv.w = f2bf(v[g4*4+3] - bf2f(hv.w));
        *(ushort4*)&Ah[idx] = hv;
        *(ushort4*)&Al[idx] = lv;
      }
    }
    // B stage (already-split gWT)
    {
      int n = tid >> 1, half = tid & 1;
      const unsigned short* bh = gWTh + (size_t)(n0 + n) * 320 + kc * 32 + half * 16;
      const unsigned short* bl = gWTl + (size_t)(n0 + n) * 320 + kc * 32 + half * 16;
      #pragma unroll
      for (int ff = 0; ff < 2; ++ff) {
        int q = half * 2 + ff;
        int idx = n * 32 + swzq(n, q) * 8;
        *(s16x8*)&Bh[idx] = *(const s16x8*)(bh + ff * 8);
        *(s16x8*)&Bl[idx] = *(const s16x8*)(bl + ff * 8);
      }
    }
    __syncthreads();
    s16x8 ah[4], alo[4];
    #pragma unroll
    for (int mf = 0; mf < 4; ++mf) {
      int row = wr * 64 + mf * 16 + lr;
      int ai = row * 32 + swzq(row, lq) * 8;
      ah[mf] = *(const s16x8*)&Ah[ai];
      alo[mf] = *(const s16x8*)&Al[ai];
    }
    #pragma unroll
    for (int nf = 0; nf < 4; ++nf) {
      int rn = wc * 64 + nf * 16 + lr;
      int bi = rn * 32 + swzq(rn, lq) * 8;
      s16x8 bhv = *(const s16x8*)&Bh[bi];
      s16x8 blv = *(const s16x8*)&Bl[bi];
      #pragma unroll
      for (int mf = 0; mf < 4; ++mf)
        acc[mf][nf] = mfma3(ah[mf], alo[mf], bhv, blv, acc[mf][nf]);
    }
    __syncthreads();
  }
  // epilogue: write zT hi/lo (transposed layout)
  int g = m0 >> 7;
  #pragma unroll
  for (int mf = 0; mf < 4; ++mf) {
    #pragma unroll
    for (int nf = 0; nf < 4; ++nf) {
      int c = n0 + wc * 64 + nf * 16 + lr;
      if (c < 1200) {
        int head = c / 300;
        int d = c - head * 300;
        int ib = wr * 64 + mf * 16 + 4 * lq;
        size_t base = ((size_t)(g * 4 + head) * 300 + d) * 128 + ib;
        f32x4 a = acc[mf][nf];
        ushort4 hv, lv;
        hv.x = f2bf(a[0]); lv.x = f2bf(a[0] - bf2f(hv.x));
        hv.y = f2bf(a[1]); lv.y = f2bf(a[1] - bf2f(hv.y));
        hv.z = f2bf(a[2]); lv.z = f2bf(a[2] - bf2f(hv.z));
        hv.w = f2bf(a[3]); lv.w = f2bf(a[3] - bf2f(hv.w));
        *(ushort4*)(zTh + base) = hv;
        *(ushort4*)(zTl + base) = lv;
      }
    }
  }
}

// ---------------- elr: el/er from zT
__global__ __launch_bounds__(128) void elr_kernel(
    const unsigned short* __restrict__ zTh, const unsigned short* __restrict__ zTl,
    const float* __restrict__ attn_l, const float* __restrict__ attn_r,
    float* __restrict__ el, float* __restrict__ er) {
  int s = blockIdx.x, g = blockIdx.y, j = threadIdx.x;
  __shared__ float aL[300], aR[300];
  for (int d = j; d < 300; d += 128) { aL[d] = attn_l[s * 300 + d]; aR[d] = attn_r[s * 300 + d]; }
  __syncthreads();
  const unsigned short* zh = zTh + (size_t)(g * 4 + s) * 300 * 128;
  const unsigned short* zl = zTl + (size_t)(g * 4 + s) * 300 * 128;
  float al_ = 0.f, ar_ = 0.f;
  for (int d = 0; d < 300; ++d) {
    float z = bf2f(zh[d * 128 + j]) + bf2f(zl[d * 128 + j]);
    al_ += z * aL[d];
    ar_ += z * aR[d];
  }
  el[(size_t)(g * 4 + s) * 128 + j] = al_;
  er[(size_t)(g * 4 + s) * 128 + j] = ar_;
}

// ---------------- alphaP: per-row softmax max & 1/sum; dinv for SAGE
__global__ __launch_bounds__(256) void alphap_kernel(
    const unsigned char* __restrict__ Agat, const unsigned char* __restrict__ Asag,
    const float* __restrict__ el, const float* __restrict__ er,
    float* __restrict__ mx, float* __restrict__ sinv, float* __restrict__ dinv) {
  int g = blockIdx.x, u = blockIdx.y;
  int tid = threadIdx.x, ww = tid >> 6, lane = tid & 63;
  if (u < 4) {
    const float* els = el + (size_t)(g * 4 + u) * 128;
    const float* ers = er + (size_t)(g * 4 + u) * 128;
    float el0 = els[lane], el1 = els[64 + lane];
    for (int i = ww; i < 128; i += 4) {
      const unsigned char* row = Agat + ((size_t)g * 128 + i) * 128;
      int m0 = row[lane], m1 = row[64 + lane];
      float eri = ers[i];
      float e0 = eri + el0; e0 = e0 >= 0.f ? e0 : 0.2f * e0;
      float e1 = eri + el1; e1 = e1 >= 0.f ? e1 : 0.2f * e1;
      float x0 = m0 ? e0 : -3.0e38f;
      float x1 = m1 ? e1 : -3.0e38f;
      float m_ = wmax(fmaxf(x0, x1));
      float p0 = m0 ? __expf(e0 - m_) : 0.f;
      float p1 = m1 ? __expf(e1 - m_) : 0.f;
      float s = wsum(p0 + p1);
      if (lane == 0) {
        mx[(size_t)(g * 4 + u) * 128 + i] = m_;
        sinv[(size_t)(g * 4 + u) * 128 + i] = 1.f / s;
      }
    }
  } else {
    for (int i = ww; i < 128; i += 4) {
      const unsigned char* row = Asag + ((size_t)g * 128 + i) * 128;
      float d = (float)(row[lane] + row[64 + lane]);
      d = wsum(d);
      if (lane == 0) dinv[(size_t)g * 128 + i] = 1.f / (d + 1.f);
    }
  }
}

// ---------------- gat_fuse: 4 GAT heads via MFMA + head weights + residual; plain stores
__global__ __launch_bounds__(256) void gat_fuse(
    const float* __restrict__ h, const unsigned char* __restrict__ Agat,
    const unsigned short* __restrict__ zTh, const unsigned short* __restrict__ zTl,
    const float* __restrict__ el, const float* __restrict__ er,
    const float* __restrict__ mx, const float* __restrict__ sinv,
    const float* __restrict__ gat_b, const float* __restrict__ headW,
    const float* __restrict__ head_b, float* __restrict__ out) {
  __shared__ __align__(16) unsigned short Bh[320 * 32], Bl[320 * 32];
  __shared__ __align__(16) unsigned short Ah[32 * 32], Al[32 * 32];
  __shared__ float hwred[2][32];
  __shared__ float wgts[32];
  int i0 = blockIdx.x * 32, g = blockIdx.y;
  int tid = threadIdx.x, w = tid >> 6, lane = tid & 63;
  int lq = lane >> 4, lr = lane & 15, wi = w & 1, wn = w >> 1;
  float hb = head_b[0];
  float outacc[10][4];
  #pragma unroll
  for (int nf = 0; nf < 10; ++nf)
    #pragma unroll
    for (int t = 0; t < 4; ++t) outacc[nf][t] = 0.f;

  for (int s = 0; s < 4; ++s) {
    f32x4 acc[10];
    #pragma unroll
    for (int nf = 0; nf < 10; ++nf) acc[nf] = (f32x4){0.f, 0.f, 0.f, 0.f};
    const float* els = el + (size_t)(g * 4 + s) * 128;
    const float* ers = er + (size_t)(g * 4 + s) * 128;
    const float* mxs = mx + (size_t)(g * 4 + s) * 128;
    const unsigned short* zsh = zTh + (size_t)(g * 4 + s) * 300 * 128;
    const unsigned short* zsl = zTl + (size_t)(g * 4 + s) * 300 * 128;

    for (int kc = 0; kc < 4; ++kc) {
      int j0 = kc * 32;
      // A stage: p = mask ? exp(leaky(er_i+el_j) - mx_i) : 0, split hi/lo
      {
        int m = tid >> 3, j4 = (tid & 7) * 4;
        int i = i0 + m;
        float eri = ers[i], mxi = mxs[i];
        const unsigned char* mrow = Agat + ((size_t)g * 128 + i) * 128 + j0 + j4;
        uchar4 msk = *(const uchar4*)mrow;
        f4 elv = *(const f4*)(els + j0 + j4);
        float p[4];
        {
          float e = eri + elv.x; e = e >= 0.f ? e : 0.2f * e; p[0] = msk.x ? __expf(e - mxi) : 0.f;
          e = eri + elv.y; e = e >= 0.f ? e : 0.2f * e; p[1] = msk.y ? __expf(e - mxi) : 0.f;
          e = eri + elv.z; e = e >= 0.f ? e : 0.2f * e; p[2] = msk.z ? __expf(e - mxi) : 0.f;
          e = eri + elv.w; e = e >= 0.f ? e : 0.2f * e; p[3] = msk.w ? __expf(e - mxi) : 0.f;
        }
        int q = j4 >> 3, wb = j4 & 7;
        int idx = m * 32 + swzq(m, q) * 8 + wb;
        ushort4 hv, lv;
        hv.x = f2bf(p[0]); lv.x = f2bf(p[0] - bf2f(hv.x));
        hv.y = f2bf(p[1]); lv.y = f2bf(p[1] - bf2f(hv.y));
        hv.z = f2bf(p[2]); lv.z = f2bf(p[2] - bf2f(hv.z));
        hv.w = f2bf(p[3]); lv.w = f2bf(p[3] - bf2f(hv.w));
        *(ushort4*)&Ah[idx] = hv;
        *(ushort4*)&Al[idx] = lv;
      }
      // B stage: zT rows (d) 0..319, zero for d>=300
      {
        #pragma unroll
        for (int rep = 0; rep < 2; ++rep) {
          int n = rep == 0 ? tid : 256 + tid;
          if (rep == 1 && tid >= 64) break;
          if (n < 300) {
            const unsigned short* src_h = zsh + (size_t)n * 128 + j0;
            const unsigned short* src_l = zsl + (size_t)n * 128 + j0;
            #pragma unroll
            for (int q = 0; q < 4; ++q) {
              int idx = n * 32 + swzq(n, q) * 8;
              *(s16x8*)&Bh[idx] = *(const s16x8*)(src_h + q * 8);
              *(s16x8*)&Bl[idx] = *(const s16x8*)(src_l + q * 8);
            }
          } else {
            s16x8 z8 = (s16x8){0,0,0,0,0,0,0,0};
            #pragma unroll
            for (int q = 0; q < 4; ++q) {
              int idx = n * 32 + swzq(n, q) * 8;
              *(s16x8*)&Bh[idx] = z8;
              *(s16x8*)&Bl[idx] = z8;
            }
          }
        }
      }
      __syncthreads();
      int rowa = wi * 16 + lr;
      int ai = rowa * 32 + swzq(rowa, lq) * 8;
      s16x8 ah = *(const s16x8*)&Ah[ai];
      s16x8 alv = *(const s16x8*)&Al[ai];
      #pragma unroll
      for (int nf = 0; nf < 10; ++nf) {
        int rn = wn * 160 + nf * 16 + lr;
        int bi = rn * 32 + swzq(rn, lq) * 8;
        s16x8 bhv = *(const s16x8*)&Bh[bi];
        s16x8 blv = *(const s16x8*)&Bl[bi];
        acc[nf] = mfma3(ah, alv, bhv, blv, acc[nf]);
      }
      __syncthreads();
    }
    // epilogue for slot s
    f4 sv4 = *(const f4*)(sinv + (size_t)(g * 4 + s) * 128 + i0 + wi * 16 + 4 * lq);
    float svf[4] = {sv4.x, sv4.y, sv4.z, sv4.w};
    float pt[4] = {0.f, 0.f, 0.f, 0.f};
    #pragma unroll
    for (int nf = 0; nf < 10; ++nf) {
      int c = wn * 160 + nf * 16 + lr;
      bool val = c < 300;
      float gb = val ? gat_b[s * 300 + c] : 0.f;
      float hwv = val ? headW[c] : 0.f;
      #pragma unroll
      for (int t = 0; t < 4; ++t) {
        float gvv = acc[nf][t] * svf[t] + gb;
        acc[nf][t] = gvv;
        pt[t] += gvv * hwv;
      }
    }
    #pragma unroll
    for (int t = 0; t < 4; ++t) {
      #pragma unroll
      for (int mm = 1; mm < 16; mm <<= 1) pt[t] += __shfl_xor(pt[t], mm, 64);
    }
    if (lr == 0) {
      #pragma unroll
      for (int t = 0; t < 4; ++t) hwred[wn][wi * 16 + 4 * lq + t] = pt[t];
    }
    __syncthreads();
    if (tid < 32) wgts[tid] = sigm(hwred[0][tid] + hwred[1][tid] + hb);
    __syncthreads();
    #pragma unroll
    for (int nf = 0; nf < 10; ++nf) {
      #pragma unroll
      for (int t = 0; t < 4; ++t) {
        int r = wi * 16 + 4 * lq + t;
        outacc[nf][t] += wgts[r] * acc[nf][t];
      }
    }
    __syncthreads();
  }
  // final: out = h + sum of weighted gat heads (sage added later)
  #pragma unroll
  for (int nf = 0; nf < 10; ++nf) {
    int c = wn * 160 + nf * 16 + lr;
    if (c < 300) {
      #pragma unroll
      for (int t = 0; t < 4; ++t) {
        int r = wi * 16 + 4 * lq + t;
        size_t o = ((size_t)(g * 128 + i0 + r)) * 300 + c;
        out[o] = h[o] + outacc[nf][t];
      }
    }
  }
}

// ---------------- neigh (fp32): n = (Asag@h + h)*dinv -> split bf16
__global__ __launch_bounds__(256) void neigh_kernel(
    const float* __restrict__ h, const unsigned char* __restrict__ Asag,
    const float* __restrict__ dinv,
    unsigned short* __restrict__ nh, unsigned short* __restrict__ nl) {
  __shared__ float As[16][128];
  int i0 = blockIdx.x * 16, g = blockIdx.y;
  int tid = threadIdx.x, ii = tid >> 6, lane = tid & 63;
  for (int idx = tid; idx < 16 * 128; idx += 256)
    As[idx >> 7][idx & 127] = (float)Asag[((size_t)g * 128 + i0 + (idx >> 7)) * 128 + (idx & 127)];
  __syncthreads();
  int dq0 = lane, dq1 = lane + 64;
  bool ok1 = dq1 < 75;
  const f4 zero4 = make_float4(0.f, 0.f, 0.f, 0.f);
  const f4* h4 = (const f4*)(h + (size_t)g * LLN * DDIM);
  f4 acc0[4], acc1[4];
  #pragma unroll
  for (int r = 0; r < 4; ++r) { acc0[r] = zero4; acc1[r] = zero4; }
  for (int j = 0; j < 128; ++j) {
    float a0 = As[ii*4+0][j], a1 = As[ii*4+1][j], a2 = As[ii*4+2][j], a3 = As[ii*4+3][j];
    f4 hv0 = h4[j * 75 + dq0];
    f4 hv1 = ok1 ? h4[j * 75 + dq1] : zero4;
    FMA4(acc0[0], hv0, a0); FMA4(acc0[1], hv0, a1); FMA4(acc0[2], hv0, a2); FMA4(acc0[3], hv0, a3);
    FMA4(acc1[0], hv1, a0); FMA4(acc1[1], hv1, a1); FMA4(acc1[2], hv1, a2); FMA4(acc1[3], hv1, a3);
  }
  #pragma unroll
  for (int r = 0; r < 4; ++r) {
    int i = i0 + ii * 4 + r;
    float dv = dinv[(size_t)g * 128 + i];
    f4 n0v = scale4(add4(acc0[r], h4[i * 75 + dq0]), dv);
    size_t base = (size_t)(g * 128 + i) * 320;
    ushort4 hv, lv;
    hv.x = f2bf(n0v.x); lv.x = f2bf(n0v.x - bf2f(hv.x));
    hv.y = f2bf(n0v.y); lv.y = f2bf(n0v.y - bf2f(hv.y));
    hv.z = f2bf(n0v.z); lv.z = f2bf(n0v.z - bf2f(hv.z));
    hv.w = f2bf(n0v.w); lv.w = f2bf(n0v.w - bf2f(hv.w));
    *(ushort4*)&nh[base + dq0 * 4] = hv;
    *(ushort4*)&nl[base + dq0 * 4] = lv;
    if (ok1) {
      f4 n1v = scale4(add4(acc1[r], h4[i * 75 + dq1]), dv);
      hv.x = f2bf(n1v.x); lv.x = f2bf(n1v.x - bf2f(hv.x));
      hv.y = f2bf(n1v.y); lv.y = f2bf(n1v.y - bf2f(hv.y));
      hv.z = f2bf(n1v.z); lv.z = f2bf(n1v.z - bf2f(hv.z));
      hv.w = f2bf(n1v.w); lv.w = f2bf(n1v.w - bf2f(hv.w));
      *(ushort4*)&nh[base + dq1 * 4] = hv;
      *(ushort4*)&nl[base + dq1 * 4] = lv;
    }
    if (lane < 5) {
      ushort4 z4u = {0, 0, 0, 0};
      *(ushort4*)&nh[base + 300 + lane * 4] = z4u;
      *(ushort4*)&nl[base + 300 + lane * 4] = z4u;
    }
  }
}

// ---------------- sage_fuse: sage = neigh@sageW + b; out += sigmoid(dot)*sage
__global__ __launch_bounds__(256) void sage_fuse(
    const unsigned short* __restrict__ nh, const unsigned short* __restrict__ nl,
    const unsigned short* __restrict__ sWTh, const unsigned short* __restrict__ sWTl,
    const float* __restrict__ sage_b, const float* __restrict__ headW,
    const float* __restrict__ head_b, float* __restrict__ out) {
  __shared__ __align__(16) unsigned short Bh[320 * 32], Bl[320 * 32];
  __shared__ __align__(16) unsigned short Ah[32 * 32], Al[32 * 32];
  __shared__ float hwred[2][32];
  __shared__ float wgts[32];
  int m0 = blockIdx.x * 32;
  int tid = threadIdx.x, w = tid >> 6, lane = tid & 63;
  int lq = lane >> 4, lr = lane & 15, wi = w & 1, wn = w >> 1;
  float hb = head_b[0];
  f32x4 acc[10];
  #pragma unroll
  for (int nf = 0; nf < 10; ++nf) acc[nf] = (f32x4){0.f, 0.f, 0.f, 0.f};

  for (int kc = 0; kc < 10; ++kc) {
    // A stage from split n
    {
      int t = tid & 127;
      int rowm = t >> 2, qq = t & 3;
      int idx = rowm * 32 + swzq(rowm, qq) * 8;
      if (tid < 128) {
        const unsigned short* src = nh + (size_t)(m0 + rowm) * 320 + kc * 32 + qq * 8;
        *(s16x8*)&Ah[idx] = *(const s16x8*)src;
      } else {
        const unsigned short* src = nl + (size_t)(m0 + rowm) * 320 + kc * 32 + qq * 8;
        *(s16x8*)&Al[idx] = *(const s16x8*)src;
      }
    }
    // B stage from sWT (rows fully padded)
    {
      #pragma unroll
      for (int rep = 0; rep < 2; ++rep) {
        int n = rep == 0 ? tid : 256 + tid;
        if (rep == 1 && tid >= 64) break;
        const unsigned short* src_h = sWTh + (size_t)n * 320 + kc * 32;
        const unsigned short* src_l = sWTl + (size_t)n * 320 + kc * 32;
        #pragma unroll
        for (int q = 0; q < 4; ++q) {
          int idx = n * 32 + swzq(n, q) * 8;
          *(s16x8*)&Bh[idx] = *(const s16x8*)(src_h + q * 8);
          *(s16x8*)&Bl[idx] = *(const s16x8*)(src_l + q * 8);
        }
      }
    }
    __syncthreads();
    int rowa = wi * 16 + lr;
    int ai = rowa * 32 + swzq(rowa, lq) * 8;
    s16x8 ah = *(const s16x8*)&Ah[ai];
    s16x8 alv = *(const s16x8*)&Al[ai];
    #pragma unroll
    for (int nf = 0; nf < 10; ++nf) {
      int rn = wn * 160 + nf * 16 + lr;
      int bi = rn * 32 + swzq(rn, lq) * 8;
      s16x8 bhv = *(const s16x8*)&Bh[bi];
      s16x8 blv = *(const s16x8*)&Bl[bi];
      acc[nf] = mfma3(ah, alv, bhv, blv, acc[nf]);
    }
    __syncthreads();
  }
  float pt[4] = {0.f, 0.f, 0.f, 0.f};
  #pragma unroll
  for (int nf = 0; nf < 10; ++nf) {
    int c = wn * 160 + nf * 16 + lr;
    bool val = c < 300;
    float sb = val ? sage_b[c] : 0.f;
    float hwv = val ? headW[c] : 0.f;
    #pragma unroll
    for (int t = 0; t < 4; ++t) {
      float gvv = acc[nf][t] + sb;
      acc[nf][t] = gvv;
      pt[t] += gvv * hwv;
    }
  }
  #pragma unroll
  for (int t = 0; t < 4; ++t) {
    #pragma unroll
    for (int mm = 1; mm < 16; mm <<= 1) pt[t] += __shfl_xor(pt[t], mm, 64);
  }
  if (lr == 0) {
    #pragma unroll
    for (int t = 0; t < 4; ++t) hwred[wn][wi * 16 + 4 * lq + t] = pt[t];
  }
  __syncthreads();
  if (tid < 32) wgts[tid] = sigm(hwred[0][tid] + hwred[1][tid] + hb);
  __syncthreads();
  #pragma unroll
  for (int nf = 0; nf < 10; ++nf) {
    int c = wn * 160 + nf * 16 + lr;
    if (c < 300) {
      #pragma unroll
      for (int t = 0; t < 4; ++t) {
        int r = wi * 16 + 4 * lq + t;
        size_t o = ((size_t)(m0 + r)) * 300 + c;
        out[o] = out[o] + wgts[r] * acc[nf][t];
      }
    }
  }
}

// ---------------- WeightAndSum pool
__global__ __launch_bounds__(256) void pool_kernel(
    const float* __restrict__ h, const float* __restrict__ poolW,
    const float* __restrict__ pool_b, float* __restrict__ gvec) {
  __shared__ float ws_[128];
  int g = blockIdx.x, tid = threadIdx.x, ii = tid >> 6, lane = tid & 63;
  const float* hg = h + (size_t)g * LLN * DDIM;
  float pb = pool_b[0];
  for (int m = 0; m < 32; ++m) {
    int l = ii * 32 + m;
    float p = 0.f;
    for (int d = lane; d < DDIM; d += 64) p += hg[l * DDIM + d] * poolW[d];
    p = wsum(p);
    if (lane == 0) ws_[l] = 1.f / (1.f + __expf(-(p + pb)));
  }
  __syncthreads();
  for (int d = tid; d < DDIM; d += 256) {
    float acc = 0.f;
    for (int l = 0; l < 128; ++l) acc += hg[l * DDIM + d] * ws_[l];
    gvec[(size_t)g * DDIM + d] = acc;
  }
}

// ---------------- pearson
__global__ __launch_bounds__(64) void pearson_kernel(
    const float* __restrict__ gvec, float* __restrict__ out) {
  int b = blockIdx.x, lane = threadIdx.x;
  const float* g1 = gvec + (size_t)b * DDIM;
  const float* g2 = gvec + (size_t)(64 + b) * DDIM;
  float v1[5], v2[5];
  float s1 = 0.f, s2 = 0.f;
  #pragma unroll
  for (int q = 0; q < 5; ++q) {
    int d = lane + 64 * q;
    v1[q] = (d < DDIM) ? g1[d] : 0.f;
    v2[q] = (d < DDIM) ? g2[d] : 0.f;
    s1 += v1[q]; s2 += v2[q];
  }
  s1 = wsum(s1); s2 = wsum(s2);
  float m1 = s1 / 300.f, m2 = s2 / 300.f;
  float a = 0.f, bb = 0.f, c = 0.f;
  #pragma unroll
  for (int q = 0; q < 5; ++q) {
    int d = lane + 64 * q;
    if (d < DDIM) {
      float x = v1[q] - m1, y = v2[q] - m2;
      a += x * y; bb += x * x; c += y * y;
    }
  }
  a = wsum(a); bb = wsum(bb); c = wsum(c);
  if (lane == 0) out[b] = 5.f * a / (sqrtf(bb) * sqrtf(c));
}

extern "C" void kernel_launch(void* const* d_in, const int* in_sizes, int n_in,
                              void* d_out, int out_size, void* d_ws, size_t ws_size,
                              hipStream_t stream) {
  (void)in_sizes; (void)n_in; (void)out_size; (void)ws_size;
  const float* emb   = (const float*)d_in[0];
  const float* simw1 = (const float*)d_in[1];
  const float* simw2 = (const float*)d_in[2];
  const float* LP[2][8];
  for (int l = 0; l < 2; ++l)
    for (int p = 0; p < 8; ++p) LP[l][p] = (const float*)d_in[3 + l * 8 + p];
  const float* poolW  = (const float*)d_in[19];
  const float* pool_b = (const float*)d_in[20];
  const int* s1 = (const int*)d_in[21];
  const int* s2 = (const int*)d_in[22];
  float* out = (float*)d_out;

  char* ws = (char*)d_ws;
  float* hA  = (float*)(ws + 0);                         // 19,660,800
  float* hB  = (float*)(ws + 19660800);                  // 19,660,800
  unsigned short* zTh = (unsigned short*)(ws + 39321600);   // 39,321,600
  unsigned short* zTl = (unsigned short*)(ws + 78643200);   // 39,321,600
  float* Vt = (float*)(ws + 39321600);                   // alias zTh (pre-zmm)
  unsigned short* nh = (unsigned short*)(ws + 39321600); // alias zTh (post-gat_fuse)
  unsigned short* nl = (unsigned short*)(ws + 78643200); // alias zTl
  unsigned char* Agat = (unsigned char*)(ws + 117964800); // 2,097,152
  unsigned char* Asag = (unsigned char*)(ws + 120061952); // 2,097,152
  float* elb  = (float*)(ws + 122159104);                // 262,144
  float* erb  = (float*)(ws + 122421248);                // 262,144
  float* mxb  = (float*)(ws + 122683392);                // 262,144
  float* sinvb= (float*)(ws + 122945536);                // 262,144
  float* dinvb= (float*)(ws + 123207680);                // 65,536
  unsigned short* gWTh = (unsigned short*)(ws + 123273216); // 819,200
  unsigned short* gWTl = (unsigned short*)(ws + 124092416); // 819,200
  unsigned short* sWTh = (unsigned short*)(ws + 124911616); // 204,800
  unsigned short* sWTl = (unsigned short*)(ws + 125116416); // 204,800
  float* gv   = (float*)(ws + 125321216);                // 153,600

  gather_kernel<<<GG * LLN, 256, 0, stream>>>(emb, s1, s2, hA);

  float* hin = hA; float* hout = hB;
  for (int l = 0; l < 2; ++l) {
    vt_kernel<<<dim3(10, 2, GG), 256, 0, stream>>>(hin, simw2, Vt);
    adj_kernel<<<dim3(4, GG), 256, 0, stream>>>(hin, simw2, Vt, Agat);
    vt_kernel<<<dim3(10, 2, GG), 256, 0, stream>>>(hin, simw1, Vt);
    adj_kernel<<<dim3(4, GG), 256, 0, stream>>>(hin, simw1, Vt, Asag);
    prepw_kernel<<<2000, 256, 0, stream>>>(LP[l][0], LP[l][4], gWTh, gWTl, sWTh, sWTl);
    zmm_mfma<<<dim3(10, 128), 256, 0, stream>>>(hin, gWTh, gWTl, zTh, zTl);
    elr_kernel<<<dim3(4, GG), 128, 0, stream>>>(zTh, zTl, LP[l][1], LP[l][2], elb, erb);
    alphap_kernel<<<dim3(GG, 5), 256, 0, stream>>>(Agat, Asag, elb, erb, mxb, sinvb, dinvb);
    gat_fuse<<<dim3(4, GG), 256, 0, stream>>>(hin, Agat, zTh, zTl, elb, erb, mxb, sinvb,
        LP[l][3], LP[l][6], LP[l][7], hout);
    neigh_kernel<<<dim3(8, GG), 256, 0, stream>>>(hin, Asag, dinvb, nh, nl);
    sage_fuse<<<512, 256, 0, stream>>>(nh, nl, sWTh, sWTl, LP[l][5], LP[l][6], LP[l][7], hout);
    float* t = hin; hin = hout; hout = t;
  }

  pool_kernel<<<GG, 256, 0, stream>>>(hin, poolW, pool_b, gv);
  pearson_kernel<<<64, 64, 0, stream>>>(gv, out);
}

// Round 4
// 923.235 us; speedup vs baseline: 1.9427x; 1.0681x over previous
//
#include <hip/hip_runtime.h>
#include <hip/hip_bf16.h>

#define GG 128   // graphs total (2 branches x 64)
#define LLN 128
#define DDIM 300
#define NH 4

typedef float4 f4;
typedef __attribute__((ext_vector_type(4))) float f32x4;
typedef __attribute__((ext_vector_type(8))) short s16x8;

__device__ __forceinline__ float wsum(float v) {
  #pragma unroll
  for (int o = 32; o > 0; o >>= 1) v += __shfl_xor(v, o, 64);
  return v;
}
__device__ __forceinline__ float wmax(float v) {
  #pragma unroll
  for (int o = 32; o > 0; o >>= 1) v = fmaxf(v, __shfl_xor(v, o, 64));
  return v;
}
__device__ __forceinline__ f4 add4(f4 a, f4 b) {
  return make_float4(a.x+b.x, a.y+b.y, a.z+b.z, a.w+b.w);
}
__device__ __forceinline__ f4 scale4(f4 a, float s) {
  return make_float4(a.x*s, a.y*s, a.z*s, a.w*s);
}
#define FMA4(acc, v, s) { (acc).x += (s)*(v).x; (acc).y += (s)*(v).y; (acc).z += (s)*(v).z; (acc).w += (s)*(v).w; }

__device__ __forceinline__ unsigned short f2bf(float x) {
  unsigned int u = __float_as_uint(x);
  return (unsigned short)((u + 0x7fffu + ((u >> 16) & 1u)) >> 16);
}
__device__ __forceinline__ float bf2f(unsigned short b) {
  return __uint_as_float(((unsigned int)b) << 16);
}
__device__ __forceinline__ int swzq(int row, int q) { return q ^ ((row >> 1) & 3); }
__device__ __forceinline__ float sigm(float x) { return 1.f / (1.f + __expf(-x)); }

__device__ __forceinline__ f32x4 mfma3(s16x8 ah, s16x8 al, s16x8 bh, s16x8 bl, f32x4 c) {
  c = __builtin_amdgcn_mfma_f32_16x16x32_bf16(ah, bh, c, 0, 0, 0);
  c = __builtin_amdgcn_mfma_f32_16x16x32_bf16(ah, bl, c, 0, 0, 0);
  c = __builtin_amdgcn_mfma_f32_16x16x32_bf16(al, bh, c, 0, 0, 0);
  return c;
}

// XCD co-location decode: nb blocks per graph all land on XCD (g%8).
// id = (g%8) + 8*(it + nb*(g/8));  nb must divide so that nb*16 graphs-groups fit.
__device__ __forceinline__ void xcd_decode4(int id, int& g, int& it) {
  int x = id & 7, t = id >> 3;   // t in 0..63
  it = t & 3; g = x + 8 * (t >> 2);
}
__device__ __forceinline__ void xcd_decode8(int id, int& g, int& it) {
  int x = id & 7, t = id >> 3;   // t in 0..127
  it = t & 7; g = x + 8 * (t >> 3);
}

// ---------------- embedding gather
__global__ __launch_bounds__(256) void gather_kernel(
    const float* __restrict__ emb, const int* __restrict__ s1,
    const int* __restrict__ s2, float* __restrict__ h) {
  int gl = blockIdx.x;
  int g = gl >> 7, l = gl & 127;
  const int* s = (g >= 64) ? s2 : s1;
  int tok = s[l * 64 + (g & 63)];
  const float* src = emb + (size_t)tok * DDIM;
  float* dst = h + (size_t)gl * DDIM;
  for (int d = threadIdx.x; d < DDIM; d += 256) dst[d] = src[d];
}

// ---------------- Vt[g][k][l] = relu(h[g][l][k] * w[k])
__global__ __launch_bounds__(256) void vt_kernel(
    const float* __restrict__ h, const float* __restrict__ w, float* __restrict__ Vt) {
  __shared__ float st[32][65];
  int kt = blockIdx.x, lt = blockIdx.y, g = blockIdx.z;
  int k0 = kt * 32, l0 = lt * 64;
  int tid = threadIdx.x;
  for (int idx = tid; idx < 64 * 32; idx += 256) {
    int ll = idx >> 5, kk = idx & 31;
    int k = k0 + kk;
    float v = 0.f;
    if (k < DDIM) v = fmaxf(h[((size_t)g * LLN + l0 + ll) * DDIM + k] * w[k], 0.f);
    st[kk][ll] = v;
  }
  __syncthreads();
  for (int idx = tid; idx < 64 * 32; idx += 256) {
    int kk = idx >> 6, l = idx & 63;
    int k = k0 + kk;
    if (k < DDIM) Vt[((size_t)g * DDIM + k) * LLN + l0 + l] = st[kk][l];
  }
}

// ---------------- adjacency -> u8   (XCD-swizzled: 4 i-tiles of a graph share an XCD L2)
__global__ __launch_bounds__(256) void adj_kernel(
    const float* __restrict__ h, const float* __restrict__ w,
    const float* __restrict__ Vt, unsigned char* __restrict__ A) {
  __shared__ float vit[DDIM][36];
  int g, it; xcd_decode4(blockIdx.x, g, it);
  int i0 = it * 32;
  int tid = threadIdx.x;
  for (int idx = tid; idx < 32 * DDIM; idx += 256) {
    int i = idx / DDIM, k = idx - i * DDIM;
    vit[k][i] = fmaxf(h[((size_t)g * LLN + i0 + i) * DDIM + k] * w[k], 0.f);
  }
  __syncthreads();
  int ii = tid >> 6, lane = tid & 63;
  float acc0[8], acc1[8];
  #pragma unroll
  for (int m = 0; m < 8; ++m) { acc0[m] = 0.f; acc1[m] = 0.f; }
  const float* vtg = Vt + (size_t)g * DDIM * LLN;
  for (int k = 0; k < DDIM; ++k) {
    f4 alo = *(const f4*)&vit[k][ii * 8];
    f4 ahi = *(const f4*)&vit[k][ii * 8 + 4];
    float vj0 = vtg[k * LLN + lane];
    float vj1 = vtg[k * LLN + 64 + lane];
    acc0[0] += alo.x * vj0; acc0[1] += alo.y * vj0; acc0[2] += alo.z * vj0; acc0[3] += alo.w * vj0;
    acc0[4] += ahi.x * vj0; acc0[5] += ahi.y * vj0; acc0[6] += ahi.z * vj0; acc0[7] += ahi.w * vj0;
    acc1[0] += alo.x * vj1; acc1[1] += alo.y * vj1; acc1[2] += alo.z * vj1; acc1[3] += alo.w * vj1;
    acc1[4] += ahi.x * vj1; acc1[5] += ahi.y * vj1; acc1[6] += ahi.z * vj1; acc1[7] += ahi.w * vj1;
  }
  unsigned char* Ag = A + ((size_t)g * LLN + i0 + ii * 8) * LLN;
  #pragma unroll
  for (int m = 0; m < 8; ++m) {
    int i = i0 + ii * 8 + m;
    Ag[m * LLN + lane]      = (acc0[m] >= 0.1f || i == lane)        ? 1 : 0;
    Ag[m * LLN + 64 + lane] = (acc1[m] >= 0.1f || i == (64 + lane)) ? 1 : 0;
  }
}

// ---------------- prepW: transpose+split weights into bf16 hi/lo, padded
// gWT [1280][320], sWT [320][320]
__global__ __launch_bounds__(256) void prepw_kernel(
    const float* __restrict__ gatW, const float* __restrict__ sageW,
    unsigned short* __restrict__ gWTh, unsigned short* __restrict__ gWTl,
    unsigned short* __restrict__ sWTh, unsigned short* __restrict__ sWTl) {
  int idx = blockIdx.x * 256 + threadIdx.x;
  if (idx < 1280 * 320) {
    int n = idx / 320, k = idx % 320;
    float v = (n < 1200 && k < 300) ? gatW[(size_t)k * 1200 + n] : 0.f;
    unsigned short hv = f2bf(v);
    gWTh[idx] = hv;
    gWTl[idx] = f2bf(v - bf2f(hv));
  } else if (idx < 1280 * 320 + 320 * 320) {
    int i2 = idx - 1280 * 320;
    int n = i2 / 320, k = i2 % 320;
    float v = (n < 300 && k < 300) ? sageW[(size_t)k * 300 + n] : 0.f;
    unsigned short hv = f2bf(v);
    sWTh[i2] = hv;
    sWTl[i2] = f2bf(v - bf2f(hv));
  }
}

// ---------------- zmm: z = h @ gatW  via split-bf16 MFMA; writes zT hi/lo
// zT layout: [(g*4+head)*300 + d][128 j]
__global__ __launch_bounds__(256) void zmm_mfma(
    const float* __restrict__ h,
    const unsigned short* __restrict__ gWTh, const unsigned short* __restrict__ gWTl,
    unsigned short* __restrict__ zTh, unsigned short* __restrict__ zTl) {
  __shared__ __align__(16) unsigned short Ah[128 * 32], Al[128 * 32];
  __shared__ __align__(16) unsigned short Bh[128 * 32], Bl[128 * 32];
  int nt = blockIdx.x, n0 = nt * 128, m0 = blockIdx.y * 128;
  int tid = threadIdx.x, w = tid >> 6, lane = tid & 63;
  int lq = lane >> 4, lr = lane & 15, wr = w >> 1, wc = w & 1;
  f32x4 acc[4][4];
  #pragma unroll
  for (int a = 0; a < 4; ++a)
    #pragma unroll
    for (int b = 0; b < 4; ++b) acc[a][b] = (f32x4){0.f, 0.f, 0.f, 0.f};

  for (int kc = 0; kc < 10; ++kc) {
    // A stage (split from fp32 h): thread -> (row m, half)
    {
      int m = tid >> 1, half = tid & 1;
      const float* hp = h + (size_t)(m0 + m) * 300;
      int kb = kc * 32 + half * 16;
      float v[16];
      if (kb + 15 < 300) {
        f4 x0 = *(const f4*)(hp + kb);
        f4 x1 = *(const f4*)(hp + kb + 4);
        f4 x2 = *(const f4*)(hp + kb + 8);
        f4 x3 = *(const f4*)(hp + kb + 12);
        v[0]=x0.x; v[1]=x0.y; v[2]=x0.z; v[3]=x0.w;
        v[4]=x1.x; v[5]=x1.y; v[6]=x1.z; v[7]=x1.w;
        v[8]=x2.x; v[9]=x2.y; v[10]=x2.z; v[11]=x2.w;
        v[12]=x3.x; v[13]=x3.y; v[14]=x3.z; v[15]=x3.w;
      } else {
        #pragma unroll
        for (int e = 0; e < 16; ++e) { int k = kb + e; v[e] = (k < 300) ? hp[k] : 0.f; }
      }
      #pragma unroll
      for (int g4 = 0; g4 < 4; ++g4) {
        int klocal = half * 16 + g4 * 4;
        int q = klocal >> 3, wb = klocal & 7;
        int idx = m * 32 + swzq(m, q) * 8 + wb;
        ushort4 hv, lv;
        hv.x = f2bf(v[g4*4+0]); lv.x = f2bf(v[g4*4+0] - bf2f(hv.x));
        hv.y = f2bf(v[g4*4+1]); lv.y = f2bf(v[g4*4+1] - bf2f(hv.y));
        hv.z = f2bf(v[g4*4+2]); lv.z = f2bf(v[g4*4+2] - bf2f(hv.z));
        hv.w = f2bf(v[g4*4+3]); lv.w = f2bf(v[g4*4+3] - bf2f(hv.w));
        *(ushort4*)&Ah[idx] = hv;
        *(ushort4*)&Al[idx] = lv;
      }
    }
    // B stage (already-split gWT)
    {
      int n = tid >> 1, half = tid & 1;
      const unsigned short* bh = gWTh + (size_t)(n0 + n) * 320 + kc * 32 + half * 16;
      const unsigned short* bl = gWTl + (size_t)(n0 + n) * 320 + kc * 32 + half * 16;
      #pragma unroll
      for (int ff = 0; ff < 2; ++ff) {
        int q = half * 2 + ff;
        int idx = n * 32 + swzq(n, q) * 8;
        *(s16x8*)&Bh[idx] = *(const s16x8*)(bh + ff * 8);
        *(s16x8*)&Bl[idx] = *(const s16x8*)(bl + ff * 8);
      }
    }
    __syncthreads();
    s16x8 ah[4], alo[4];
    #pragma unroll
    for (int mf = 0; mf < 4; ++mf) {
      int row = wr * 64 + mf * 16 + lr;
      int ai = row * 32 + swzq(row, lq) * 8;
      ah[mf] = *(const s16x8*)&Ah[ai];
      alo[mf] = *(const s16x8*)&Al[ai];
    }
    #pragma unroll
    for (int nf = 0; nf < 4; ++nf) {
      int rn = wc * 64 + nf * 16 + lr;
      int bi = rn * 32 + swzq(rn, lq) * 8;
      s16x8 bhv = *(const s16x8*)&Bh[bi];
      s16x8 blv = *(const s16x8*)&Bl[bi];
      #pragma unroll
      for (int mf = 0; mf < 4; ++mf)
        acc[mf][nf] = mfma3(ah[mf], alo[mf], bhv, blv, acc[mf][nf]);
    }
    __syncthreads();
  }
  // epilogue: write zT hi/lo (transposed layout)
  int g = m0 >> 7;
  #pragma unroll
  for (int mf = 0; mf < 4; ++mf) {
    #pragma unroll
    for (int nf = 0; nf < 4; ++nf) {
      int c = n0 + wc * 64 + nf * 16 + lr;
      if (c < 1200) {
        int head = c / 300;
        int d = c - head * 300;
        int ib = wr * 64 + mf * 16 + 4 * lq;
        size_t base = ((size_t)(g * 4 + head) * 300 + d) * 128 + ib;
        f32x4 a = acc[mf][nf];
        ushort4 hv, lv;
        hv.x = f2bf(a[0]); lv.x = f2bf(a[0] - bf2f(hv.x));
        hv.y = f2bf(a[1]); lv.y = f2bf(a[1] - bf2f(hv.y));
        hv.z = f2bf(a[2]); lv.z = f2bf(a[2] - bf2f(hv.z));
        hv.w = f2bf(a[3]); lv.w = f2bf(a[3] - bf2f(hv.w));
        *(ushort4*)(zTh + base) = hv;
        *(ushort4*)(zTl + base) = lv;
      }
    }
  }
}

// ---------------- elr: el/er from zT
__global__ __launch_bounds__(128) void elr_kernel(
    const unsigned short* __restrict__ zTh, const unsigned short* __restrict__ zTl,
    const float* __restrict__ attn_l, const float* __restrict__ attn_r,
    float* __restrict__ el, float* __restrict__ er) {
  int s = blockIdx.x, g = blockIdx.y, j = threadIdx.x;
  __shared__ float aL[300], aR[300];
  for (int d = j; d < 300; d += 128) { aL[d] = attn_l[s * 300 + d]; aR[d] = attn_r[s * 300 + d]; }
  __syncthreads();
  const unsigned short* zh = zTh + (size_t)(g * 4 + s) * 300 * 128;
  const unsigned short* zl = zTl + (size_t)(g * 4 + s) * 300 * 128;
  float al_ = 0.f, ar_ = 0.f;
  for (int d = 0; d < 300; ++d) {
    float z = bf2f(zh[d * 128 + j]) + bf2f(zl[d * 128 + j]);
    al_ += z * aL[d];
    ar_ += z * aR[d];
  }
  el[(size_t)(g * 4 + s) * 128 + j] = al_;
  er[(size_t)(g * 4 + s) * 128 + j] = ar_;
}

// ---------------- alphaP: per-row softmax max & 1/sum; dinv for SAGE
__global__ __launch_bounds__(256) void alphap_kernel(
    const unsigned char* __restrict__ Agat, const unsigned char* __restrict__ Asag,
    const float* __restrict__ el, const float* __restrict__ er,
    float* __restrict__ mx, float* __restrict__ sinv, float* __restrict__ dinv) {
  int g = blockIdx.x, u = blockIdx.y;
  int tid = threadIdx.x, ww = tid >> 6, lane = tid & 63;
  if (u < 4) {
    const float* els = el + (size_t)(g * 4 + u) * 128;
    const float* ers = er + (size_t)(g * 4 + u) * 128;
    float el0 = els[lane], el1 = els[64 + lane];
    for (int i = ww; i < 128; i += 4) {
      const unsigned char* row = Agat + ((size_t)g * 128 + i) * 128;
      int m0 = row[lane], m1 = row[64 + lane];
      float eri = ers[i];
      float e0 = eri + el0; e0 = e0 >= 0.f ? e0 : 0.2f * e0;
      float e1 = eri + el1; e1 = e1 >= 0.f ? e1 : 0.2f * e1;
      float x0 = m0 ? e0 : -3.0e38f;
      float x1 = m1 ? e1 : -3.0e38f;
      float m_ = wmax(fmaxf(x0, x1));
      float p0 = m0 ? __expf(e0 - m_) : 0.f;
      float p1 = m1 ? __expf(e1 - m_) : 0.f;
      float s = wsum(p0 + p1);
      if (lane == 0) {
        mx[(size_t)(g * 4 + u) * 128 + i] = m_;
        sinv[(size_t)(g * 4 + u) * 128 + i] = 1.f / s;
      }
    }
  } else {
    for (int i = ww; i < 128; i += 4) {
      const unsigned char* row = Asag + ((size_t)g * 128 + i) * 128;
      float d = (float)(row[lane] + row[64 + lane]);
      d = wsum(d);
      if (lane == 0) dinv[(size_t)g * 128 + i] = 1.f / (d + 1.f);
    }
  }
}

// ---------------- gat_fuse: 4 GAT heads via MFMA + head weights + residual
// XCD-swizzled: 4 i-tiles of a graph share an XCD so the per-graph z slot is read
// from HBM ~once and hit in that XCD's L2 for the other 3 blocks.
__global__ __launch_bounds__(256) void gat_fuse(
    const float* __restrict__ h, const unsigned char* __restrict__ Agat,
    const unsigned short* __restrict__ zTh, const unsigned short* __restrict__ zTl,
    const float* __restrict__ el, const float* __restrict__ er,
    const float* __restrict__ mx, const float* __restrict__ sinv,
    const float* __restrict__ gat_b, const float* __restrict__ headW,
    const float* __restrict__ head_b, float* __restrict__ out) {
  __shared__ __align__(16) unsigned short Bh[320 * 32], Bl[320 * 32];
  __shared__ __align__(16) unsigned short Ah[32 * 32], Al[32 * 32];
  __shared__ float hwred[2][32];
  __shared__ float wgts[32];
  int g, it; xcd_decode4(blockIdx.x, g, it);
  int i0 = it * 32;
  int tid = threadIdx.x, w = tid >> 6, lane = tid & 63;
  int lq = lane >> 4, lr = lane & 15, wi = w & 1, wn = w >> 1;
  float hb = head_b[0];
  float outacc[10][4];
  #pragma unroll
  for (int nf = 0; nf < 10; ++nf)
    #pragma unroll
    for (int t = 0; t < 4; ++t) outacc[nf][t] = 0.f;

  for (int s = 0; s < 4; ++s) {
    f32x4 acc[10];
    #pragma unroll
    for (int nf = 0; nf < 10; ++nf) acc[nf] = (f32x4){0.f, 0.f, 0.f, 0.f};
    const float* els = el + (size_t)(g * 4 + s) * 128;
    const float* ers = er + (size_t)(g * 4 + s) * 128;
    const float* mxs = mx + (size_t)(g * 4 + s) * 128;
    const unsigned short* zsh = zTh + (size_t)(g * 4 + s) * 300 * 128;
    const unsigned short* zsl = zTl + (size_t)(g * 4 + s) * 300 * 128;

    for (int kc = 0; kc < 4; ++kc) {
      int j0 = kc * 32;
      // A stage: p = mask ? exp(leaky(er_i+el_j) - mx_i) : 0, split hi/lo
      {
        int m = tid >> 3, j4 = (tid & 7) * 4;
        int i = i0 + m;
        float eri = ers[i], mxi = mxs[i];
        const unsigned char* mrow = Agat + ((size_t)g * 128 + i) * 128 + j0 + j4;
        uchar4 msk = *(const uchar4*)mrow;
        f4 elv = *(const f4*)(els + j0 + j4);
        float p[4];
        {
          float e = eri + elv.x; e = e >= 0.f ? e : 0.2f * e; p[0] = msk.x ? __expf(e - mxi) : 0.f;
          e = eri + elv.y; e = e >= 0.f ? e : 0.2f * e; p[1] = msk.y ? __expf(e - mxi) : 0.f;
          e = eri + elv.z; e = e >= 0.f ? e : 0.2f * e; p[2] = msk.z ? __expf(e - mxi) : 0.f;
          e = eri + elv.w; e = e >= 0.f ? e : 0.2f * e; p[3] = msk.w ? __expf(e - mxi) : 0.f;
        }
        int q = j4 >> 3, wb = j4 & 7;
        int idx = m * 32 + swzq(m, q) * 8 + wb;
        ushort4 hv, lv;
        hv.x = f2bf(p[0]); lv.x = f2bf(p[0] - bf2f(hv.x));
        hv.y = f2bf(p[1]); lv.y = f2bf(p[1] - bf2f(hv.y));
        hv.z = f2bf(p[2]); lv.z = f2bf(p[2] - bf2f(hv.z));
        hv.w = f2bf(p[3]); lv.w = f2bf(p[3] - bf2f(hv.w));
        *(ushort4*)&Ah[idx] = hv;
        *(ushort4*)&Al[idx] = lv;
      }
      // B stage: zT rows (d) 0..319, zero for d>=300
      {
        #pragma unroll
        for (int rep = 0; rep < 2; ++rep) {
          int n = rep == 0 ? tid : 256 + tid;
          if (rep == 1 && tid >= 64) break;
          if (n < 300) {
            const unsigned short* src_h = zsh + (size_t)n * 128 + j0;
            const unsigned short* src_l = zsl + (size_t)n * 128 + j0;
            #pragma unroll
            for (int q = 0; q < 4; ++q) {
              int idx = n * 32 + swzq(n, q) * 8;
              *(s16x8*)&Bh[idx] = *(const s16x8*)(src_h + q * 8);
              *(s16x8*)&Bl[idx] = *(const s16x8*)(src_l + q * 8);
            }
          } else {
            s16x8 z8 = (s16x8){0,0,0,0,0,0,0,0};
            #pragma unroll
            for (int q = 0; q < 4; ++q) {
              int idx = n * 32 + swzq(n, q) * 8;
              *(s16x8*)&Bh[idx] = z8;
              *(s16x8*)&Bl[idx] = z8;
            }
          }
        }
      }
      __syncthreads();
      int rowa = wi * 16 + lr;
      int ai = rowa * 32 + swzq(rowa, lq) * 8;
      s16x8 ah = *(const s16x8*)&Ah[ai];
      s16x8 alv = *(const s16x8*)&Al[ai];
      #pragma unroll
      for (int nf = 0; nf < 10; ++nf) {
        int rn = wn * 160 + nf * 16 + lr;
        int bi = rn * 32 + swzq(rn, lq) * 8;
        s16x8 bhv = *(const s16x8*)&Bh[bi];
        s16x8 blv = *(const s16x8*)&Bl[bi];
        acc[nf] = mfma3(ah, alv, bhv, blv, acc[nf]);
      }
      __syncthreads();
    }
    // epilogue for slot s
    f4 sv4 = *(const f4*)(sinv + (size_t)(g * 4 + s) * 128 + i0 + wi * 16 + 4 * lq);
    float svf[4] = {sv4.x, sv4.y, sv4.z, sv4.w};
    float pt[4] = {0.f, 0.f, 0.f, 0.f};
    #pragma unroll
    for (int nf = 0; nf < 10; ++nf) {
      int c = wn * 160 + nf * 16 + lr;
      bool val = c < 300;
      float gb = val ? gat_b[s * 300 + c] : 0.f;
      float hwv = val ? headW[c] : 0.f;
      #pragma unroll
      for (int t = 0; t < 4; ++t) {
        float gvv = acc[nf][t] * svf[t] + gb;
        acc[nf][t] = gvv;
        pt[t] += gvv * hwv;
      }
    }
    #pragma unroll
    for (int t = 0; t < 4; ++t) {
      #pragma unroll
      for (int mm = 1; mm < 16; mm <<= 1) pt[t] += __shfl_xor(pt[t], mm, 64);
    }
    if (lr == 0) {
      #pragma unroll
      for (int t = 0; t < 4; ++t) hwred[wn][wi * 16 + 4 * lq + t] = pt[t];
    }
    __syncthreads();
    if (tid < 32) wgts[tid] = sigm(hwred[0][tid] + hwred[1][tid] + hb);
    __syncthreads();
    #pragma unroll
    for (int nf = 0; nf < 10; ++nf) {
      #pragma unroll
      for (int t = 0; t < 4; ++t) {
        int r = wi * 16 + 4 * lq + t;
        outacc[nf][t] += wgts[r] * acc[nf][t];
      }
    }
    __syncthreads();
  }
  // final: out = h + sum of weighted gat heads (sage added later)
  #pragma unroll
  for (int nf = 0; nf < 10; ++nf) {
    int c = wn * 160 + nf * 16 + lr;
    if (c < 300) {
      #pragma unroll
      for (int t = 0; t < 4; ++t) {
        int r = wi * 16 + 4 * lq + t;
        size_t o = ((size_t)(g * 128 + i0 + r)) * 300 + c;
        out[o] = h[o] + outacc[nf][t];
      }
    }
  }
}

// ---------------- neigh (fp32): n = (Asag@h + h)*dinv -> split bf16
// XCD-swizzled: 8 i-tiles of a graph share an XCD (h graph slice reused from L2)
__global__ __launch_bounds__(256) void neigh_kernel(
    const float* __restrict__ h, const unsigned char* __restrict__ Asag,
    const float* __restrict__ dinv,
    unsigned short* __restrict__ nh, unsigned short* __restrict__ nl) {
  __shared__ float As[16][128];
  int g, it; xcd_decode8(blockIdx.x, g, it);
  int i0 = it * 16;
  int tid = threadIdx.x, ii = tid >> 6, lane = tid & 63;
  for (int idx = tid; idx < 16 * 128; idx += 256)
    As[idx >> 7][idx & 127] = (float)Asag[((size_t)g * 128 + i0 + (idx >> 7)) * 128 + (idx & 127)];
  __syncthreads();
  int dq0 = lane, dq1 = lane + 64;
  bool ok1 = dq1 < 75;
  const f4 zero4 = make_float4(0.f, 0.f, 0.f, 0.f);
  const f4* h4 = (const f4*)(h + (size_t)g * LLN * DDIM);
  f4 acc0[4], acc1[4];
  #pragma unroll
  for (int r = 0; r < 4; ++r) { acc0[r] = zero4; acc1[r] = zero4; }
  for (int j = 0; j < 128; ++j) {
    float a0 = As[ii*4+0][j], a1 = As[ii*4+1][j], a2 = As[ii*4+2][j], a3 = As[ii*4+3][j];
    f4 hv0 = h4[j * 75 + dq0];
    f4 hv1 = ok1 ? h4[j * 75 + dq1] : zero4;
    FMA4(acc0[0], hv0, a0); FMA4(acc0[1], hv0, a1); FMA4(acc0[2], hv0, a2); FMA4(acc0[3], hv0, a3);
    FMA4(acc1[0], hv1, a0); FMA4(acc1[1], hv1, a1); FMA4(acc1[2], hv1, a2); FMA4(acc1[3], hv1, a3);
  }
  #pragma unroll
  for (int r = 0; r < 4; ++r) {
    int i = i0 + ii * 4 + r;
    float dv = dinv[(size_t)g * 128 + i];
    f4 n0v = scale4(add4(acc0[r], h4[i * 75 + dq0]), dv);
    size_t base = (size_t)(g * 128 + i) * 320;
    ushort4 hv, lv;
    hv.x = f2bf(n0v.x); lv.x = f2bf(n0v.x - bf2f(hv.x));
    hv.y = f2bf(n0v.y); lv.y = f2bf(n0v.y - bf2f(hv.y));
    hv.z = f2bf(n0v.z); lv.z = f2bf(n0v.z - bf2f(hv.z));
    hv.w = f2bf(n0v.w); lv.w = f2bf(n0v.w - bf2f(hv.w));
    *(ushort4*)&nh[base + dq0 * 4] = hv;
    *(ushort4*)&nl[base + dq0 * 4] = lv;
    if (ok1) {
      f4 n1v = scale4(add4(acc1[r], h4[i * 75 + dq1]), dv);
      hv.x = f2bf(n1v.x); lv.x = f2bf(n1v.x - bf2f(hv.x));
      hv.y = f2bf(n1v.y); lv.y = f2bf(n1v.y - bf2f(hv.y));
      hv.z = f2bf(n1v.z); lv.z = f2bf(n1v.z - bf2f(hv.z));
      hv.w = f2bf(n1v.w); lv.w = f2bf(n1v.w - bf2f(hv.w));
      *(ushort4*)&nh[base + dq1 * 4] = hv;
      *(ushort4*)&nl[base + dq1 * 4] = lv;
    }
    if (lane < 5) {
      ushort4 z4u = {0, 0, 0, 0};
      *(ushort4*)&nh[base + 300 + lane * 4] = z4u;
      *(ushort4*)&nl[base + 300 + lane * 4] = z4u;
    }
  }
}

// ---------------- sage_fuse: sage = neigh@sageW + b; out += sigmoid(dot)*sage
__global__ __launch_bounds__(256) void sage_fuse(
    const unsigned short* __restrict__ nh, const unsigned short* __restrict__ nl,
    const unsigned short* __restrict__ sWTh, const unsigned short* __restrict__ sWTl,
    const float* __restrict__ sage_b, const float* __restrict__ headW,
    const float* __restrict__ head_b, float* __restrict__ out) {
  __shared__ __align__(16) unsigned short Bh[320 * 32], Bl[320 * 32];
  __shared__ __align__(16) unsigned short Ah[32 * 32], Al[32 * 32];
  __shared__ float hwred[2][32];
  __shared__ float wgts[32];
  int m0 = blockIdx.x * 32;
  int tid = threadIdx.x, w = tid >> 6, lane = tid & 63;
  int lq = lane >> 4, lr = lane & 15, wi = w & 1, wn = w >> 1;
  float hb = head_b[0];
  f32x4 acc[10];
  #pragma unroll
  for (int nf = 0; nf < 10; ++nf) acc[nf] = (f32x4){0.f, 0.f, 0.f, 0.f};

  for (int kc = 0; kc < 10; ++kc) {
    // A stage from split n
    {
      int t = tid & 127;
      int rowm = t >> 2, qq = t & 3;
      int idx = rowm * 32 + swzq(rowm, qq) * 8;
      if (tid < 128) {
        const unsigned short* src = nh + (size_t)(m0 + rowm) * 320 + kc * 32 + qq * 8;
        *(s16x8*)&Ah[idx] = *(const s16x8*)src;
      } else {
        const unsigned short* src = nl + (size_t)(m0 + rowm) * 320 + kc * 32 + qq * 8;
        *(s16x8*)&Al[idx] = *(const s16x8*)src;
      }
    }
    // B stage from sWT (rows fully padded)
    {
      #pragma unroll
      for (int rep = 0; rep < 2; ++rep) {
        int n = rep == 0 ? tid : 256 + tid;
        if (rep == 1 && tid >= 64) break;
        const unsigned short* src_h = sWTh + (size_t)n * 320 + kc * 32;
        const unsigned short* src_l = sWTl + (size_t)n * 320 + kc * 32;
        #pragma unroll
        for (int q = 0; q < 4; ++q) {
          int idx = n * 32 + swzq(n, q) * 8;
          *(s16x8*)&Bh[idx] = *(const s16x8*)(src_h + q * 8);
          *(s16x8*)&Bl[idx] = *(const s16x8*)(src_l + q * 8);
        }
      }
    }
    __syncthreads();
    int rowa = wi * 16 + lr;
    int ai = rowa * 32 + swzq(rowa, lq) * 8;
    s16x8 ah = *(const s16x8*)&Ah[ai];
    s16x8 alv = *(const s16x8*)&Al[ai];
    #pragma unroll
    for (int nf = 0; nf < 10; ++nf) {
      int rn = wn * 160 + nf * 16 + lr;
      int bi = rn * 32 + swzq(rn, lq) * 8;
      s16x8 bhv = *(const s16x8*)&Bh[bi];
      s16x8 blv = *(const s16x8*)&Bl[bi];
      acc[nf] = mfma3(ah, alv, bhv, blv, acc[nf]);
    }
    __syncthreads();
  }
  float pt[4] = {0.f, 0.f, 0.f, 0.f};
  #pragma unroll
  for (int nf = 0; nf < 10; ++nf) {
    int c = wn * 160 + nf * 16 + lr;
    bool val = c < 300;
    float sb = val ? sage_b[c] : 0.f;
    float hwv = val ? headW[c] : 0.f;
    #pragma unroll
    for (int t = 0; t < 4; ++t) {
      float gvv = acc[nf][t] + sb;
      acc[nf][t] = gvv;
      pt[t] += gvv * hwv;
    }
  }
  #pragma unroll
  for (int t = 0; t < 4; ++t) {
    #pragma unroll
    for (int mm = 1; mm < 16; mm <<= 1) pt[t] += __shfl_xor(pt[t], mm, 64);
  }
  if (lr == 0) {
    #pragma unroll
    for (int t = 0; t < 4; ++t) hwred[wn][wi * 16 + 4 * lq + t] = pt[t];
  }
  __syncthreads();
  if (tid < 32) wgts[tid] = sigm(hwred[0][tid] + hwred[1][tid] + hb);
  __syncthreads();
  #pragma unroll
  for (int nf = 0; nf < 10; ++nf) {
    int c = wn * 160 + nf * 16 + lr;
    if (c < 300) {
      #pragma unroll
      for (int t = 0; t < 4; ++t) {
        int r = wi * 16 + 4 * lq + t;
        size_t o = ((size_t)(m0 + r)) * 300 + c;
        out[o] = out[o] + wgts[r] * acc[nf][t];
      }
    }
  }
}

// ---------------- WeightAndSum pool
__global__ __launch_bounds__(256) void pool_kernel(
    const float* __restrict__ h, const float* __restrict__ poolW,
    const float* __restrict__ pool_b, float* __restrict__ gvec) {
  __shared__ float ws_[128];
  int g = blockIdx.x, tid = threadIdx.x, ii = tid >> 6, lane = tid & 63;
  const float* hg = h + (size_t)g * LLN * DDIM;
  float pb = pool_b[0];
  for (int m = 0; m < 32; ++m) {
    int l = ii * 32 + m;
    float p = 0.f;
    for (int d = lane; d < DDIM; d += 64) p += hg[l * DDIM + d] * poolW[d];
    p = wsum(p);
    if (lane == 0) ws_[l] = 1.f / (1.f + __expf(-(p + pb)));
  }
  __syncthreads();
  for (int d = tid; d < DDIM; d += 256) {
    float acc = 0.f;
    for (int l = 0; l < 128; ++l) acc += hg[l * DDIM + d] * ws_[l];
    gvec[(size_t)g * DDIM + d] = acc;
  }
}

// ---------------- pearson
__global__ __launch_bounds__(64) void pearson_kernel(
    const float* __restrict__ gvec, float* __restrict__ out) {
  int b = blockIdx.x, lane = threadIdx.x;
  const float* g1 = gvec + (size_t)b * DDIM;
  const float* g2 = gvec + (size_t)(64 + b) * DDIM;
  float v1[5], v2[5];
  float s1 = 0.f, s2 = 0.f;
  #pragma unroll
  for (int q = 0; q < 5; ++q) {
    int d = lane + 64 * q;
    v1[q] = (d < DDIM) ? g1[d] : 0.f;
    v2[q] = (d < DDIM) ? g2[d] : 0.f;
    s1 += v1[q]; s2 += v2[q];
  }
  s1 = wsum(s1); s2 = wsum(s2);
  float m1 = s1 / 300.f, m2 = s2 / 300.f;
  float a = 0.f, bb = 0.f, c = 0.f;
  #pragma unroll
  for (int q = 0; q < 5; ++q) {
    int d = lane + 64 * q;
    if (d < DDIM) {
      float x = v1[q] - m1, y = v2[q] - m2;
      a += x * y; bb += x * x; c += y * y;
    }
  }
  a = wsum(a); bb = wsum(bb); c = wsum(c);
  if (lane == 0) out[b] = 5.f * a / (sqrtf(bb) * sqrtf(c));
}

extern "C" void kernel_launch(void* const* d_in, const int* in_sizes, int n_in,
                              void* d_out, int out_size, void* d_ws, size_t ws_size,
                              hipStream_t stream) {
  (void)in_sizes; (void)n_in; (void)out_size; (void)ws_size;
  const float* emb   = (const float*)d_in[0];
  const float* simw1 = (const float*)d_in[1];
  const float* simw2 = (const float*)d_in[2];
  const float* LP[2][8];
  for (int l = 0; l < 2; ++l)
    for (int p = 0; p < 8; ++p) LP[l][p] = (const float*)d_in[3 + l * 8 + p];
  const float* poolW  = (const float*)d_in[19];
  const float* pool_b = (const float*)d_in[20];
  const int* s1 = (const int*)d_in[21];
  const int* s2 = (const int*)d_in[22];
  float* out = (float*)d_out;

  char* ws = (char*)d_ws;
  float* hA  = (float*)(ws + 0);                         // 19,660,800
  float* hB  = (float*)(ws + 19660800);                  // 19,660,800
  unsigned short* zTh = (unsigned short*)(ws + 39321600);   // 39,321,600
  unsigned short* zTl = (unsigned short*)(ws + 78643200);   // 39,321,600
  float* Vt = (float*)(ws + 39321600);                   // alias zTh (pre-zmm)
  unsigned short* nh = (unsigned short*)(ws + 39321600); // alias zTh (post-gat_fuse)
  unsigned short* nl = (unsigned short*)(ws + 78643200); // alias zTl
  unsigned char* Agat = (unsigned char*)(ws + 117964800); // 2,097,152
  unsigned char* Asag = (unsigned char*)(ws + 120061952); // 2,097,152
  float* elb  = (float*)(ws + 122159104);                // 262,144
  float* erb  = (float*)(ws + 122421248);                // 262,144
  float* mxb  = (float*)(ws + 122683392);                // 262,144
  float* sinvb= (float*)(ws + 122945536);                // 262,144
  float* dinvb= (float*)(ws + 123207680);                // 65,536
  unsigned short* gWTh = (unsigned short*)(ws + 123273216); // 819,200
  unsigned short* gWTl = (unsigned short*)(ws + 124092416); // 819,200
  unsigned short* sWTh = (unsigned short*)(ws + 124911616); // 204,800
  unsigned short* sWTl = (unsigned short*)(ws + 125116416); // 204,800
  float* gv   = (float*)(ws + 125321216);                // 153,600

  gather_kernel<<<GG * LLN, 256, 0, stream>>>(emb, s1, s2, hA);

  float* hin = hA; float* hout = hB;
  for (int l = 0; l < 2; ++l) {
    vt_kernel<<<dim3(10, 2, GG), 256, 0, stream>>>(hin, simw2, Vt);
    adj_kernel<<<512, 256, 0, stream>>>(hin, simw2, Vt, Agat);
    vt_kernel<<<dim3(10, 2, GG), 256, 0, stream>>>(hin, simw1, Vt);
    adj_kernel<<<512, 256, 0, stream>>>(hin, simw1, Vt, Asag);
    prepw_kernel<<<2000, 256, 0, stream>>>(LP[l][0], LP[l][4], gWTh, gWTl, sWTh, sWTl);
    zmm_mfma<<<dim3(10, 128), 256, 0, stream>>>(hin, gWTh, gWTl, zTh, zTl);
    elr_kernel<<<dim3(4, GG), 128, 0, stream>>>(zTh, zTl, LP[l][1], LP[l][2], elb, erb);
    alphap_kernel<<<dim3(GG, 5), 256, 0, stream>>>(Agat, Asag, elb, erb, mxb, sinvb, dinvb);
    gat_fuse<<<512, 256, 0, stream>>>(hin, Agat, zTh, zTl, elb, erb, mxb, sinvb,
        LP[l][3], LP[l][6], LP[l][7], hout);
    neigh_kernel<<<1024, 256, 0, stream>>>(hin, Asag, dinvb, nh, nl);
    sage_fuse<<<512, 256, 0, stream>>>(nh, nl, sWTh, sWTl, LP[l][5], LP[l][6], LP[l][7], hout);
    float* t = hin; hin = hout; hout = t;
  }

  pool_kernel<<<GG, 256, 0, stream>>>(hin, poolW, pool_b, gv);
  pearson_kernel<<<64, 64, 0, stream>>>(gv, out);
}

// Round 5
// 764.569 us; speedup vs baseline: 2.3458x; 1.2075x over previous
//
#include <hip/hip_runtime.h>
#include <hip/hip_bf16.h>

#define GG 128   // graphs total (2 branches x 64)
#define LLN 128
#define DDIM 300
#define NH 4

typedef float4 f4;
typedef __attribute__((ext_vector_type(4))) float f32x4;
typedef __attribute__((ext_vector_type(8))) short s16x8;

__device__ __forceinline__ float wsum(float v) {
  #pragma unroll
  for (int o = 32; o > 0; o >>= 1) v += __shfl_xor(v, o, 64);
  return v;
}
__device__ __forceinline__ float wmax(float v) {
  #pragma unroll
  for (int o = 32; o > 0; o >>= 1) v = fmaxf(v, __shfl_xor(v, o, 64));
  return v;
}
__device__ __forceinline__ f4 add4(f4 a, f4 b) {
  return make_float4(a.x+b.x, a.y+b.y, a.z+b.z, a.w+b.w);
}
__device__ __forceinline__ f4 scale4(f4 a, float s) {
  return make_float4(a.x*s, a.y*s, a.z*s, a.w*s);
}
#define FMA4(acc, v, s) { (acc).x += (s)*(v).x; (acc).y += (s)*(v).y; (acc).z += (s)*(v).z; (acc).w += (s)*(v).w; }

__device__ __forceinline__ unsigned short f2bf(float x) {
  unsigned int u = __float_as_uint(x);
  return (unsigned short)((u + 0x7fffu + ((u >> 16) & 1u)) >> 16);
}
__device__ __forceinline__ float bf2f(unsigned short b) {
  return __uint_as_float(((unsigned int)b) << 16);
}
__device__ __forceinline__ int swzq(int row, int q) { return q ^ ((row >> 1) & 3); }
__device__ __forceinline__ float sigm(float x) { return 1.f / (1.f + __expf(-x)); }

__device__ __forceinline__ f32x4 mfma3(s16x8 ah, s16x8 al, s16x8 bh, s16x8 bl, f32x4 c) {
  c = __builtin_amdgcn_mfma_f32_16x16x32_bf16(ah, bh, c, 0, 0, 0);
  c = __builtin_amdgcn_mfma_f32_16x16x32_bf16(ah, bl, c, 0, 0, 0);
  c = __builtin_amdgcn_mfma_f32_16x16x32_bf16(al, bh, c, 0, 0, 0);
  return c;
}
__device__ __forceinline__ f32x4 mfma4(s16x8 ah, s16x8 al, s16x8 bh, s16x8 bl, f32x4 c) {
  c = __builtin_amdgcn_mfma_f32_16x16x32_bf16(ah, bh, c, 0, 0, 0);
  c = __builtin_amdgcn_mfma_f32_16x16x32_bf16(ah, bl, c, 0, 0, 0);
  c = __builtin_amdgcn_mfma_f32_16x16x32_bf16(al, bh, c, 0, 0, 0);
  c = __builtin_amdgcn_mfma_f32_16x16x32_bf16(al, bl, c, 0, 0, 0);
  return c;
}

__device__ __forceinline__ void xcd_decode8(int id, int& g, int& it) {
  int x = id & 7, t = id >> 3;
  it = t & 7; g = x + 8 * (t >> 3);
}

// ---------------- embedding gather
__global__ __launch_bounds__(256) void gather_kernel(
    const float* __restrict__ emb, const int* __restrict__ s1,
    const int* __restrict__ s2, float* __restrict__ h) {
  int gl = blockIdx.x;
  int g = gl >> 7, l = gl & 127;
  const int* s = (g >= 64) ? s2 : s1;
  int tok = s[l * 64 + (g & 63)];
  const float* src = emb + (size_t)tok * DDIM;
  float* dst = h + (size_t)gl * DDIM;
  for (int d = threadIdx.x; d < DDIM; d += 256) dst[d] = src[d];
}

// ---------------- adjmm: both adjacencies via 4-term split-bf16 MFMA (V.V^T, symmetric)
// grid 512: id -> x=id&7 (XCD), t=id>>3, sub=t&3 (u=sub&1, half=sub>>1), g=x+8*(t>>2)
// All 4 blocks of graph g co-located on one XCD -> h slice fetched once.
__global__ __launch_bounds__(256) void adjmm_kernel(
    const float* __restrict__ h, const float* __restrict__ simw1,
    const float* __restrict__ simw2, unsigned char* __restrict__ Agat,
    unsigned char* __restrict__ Asag) {
  __shared__ __align__(16) unsigned short Vh[128 * 32], Vl[128 * 32];
  __shared__ float wv[320];
  int x = blockIdx.x & 7, t = blockIdx.x >> 3;
  int sub = t & 3, g = x + 8 * (t >> 2);
  int u = sub & 1, half = sub >> 1;
  const float* w = u ? simw1 : simw2;
  unsigned char* A = (u ? Asag : Agat) + (size_t)g * LLN * LLN;
  int tid = threadIdx.x, wid = tid >> 6, lane = tid & 63;
  int lq = lane >> 4, lr = lane & 15;
  for (int k = tid; k < 320; k += 256) wv[k] = (k < 300) ? w[k] : 0.f;
  f32x4 acc[8];
  #pragma unroll
  for (int nf = 0; nf < 8; ++nf) acc[nf] = (f32x4){0.f, 0.f, 0.f, 0.f};
  const float* hg = h + (size_t)g * LLN * DDIM;

  for (int kc = 0; kc < 10; ++kc) {
    __syncthreads();   // wv ready (kc=0) / previous-iter frag reads done
    // stage V tile: rows 0..127 x k 32 (shared as A and B operand)
    {
      int m = tid >> 1, halfk = tid & 1;
      int kb = kc * 32 + halfk * 16;
      const float* hp = hg + (size_t)m * DDIM;
      float v[16];
      if (kb + 15 < 300) {
        f4 x0 = *(const f4*)(hp + kb);
        f4 x1 = *(const f4*)(hp + kb + 4);
        f4 x2 = *(const f4*)(hp + kb + 8);
        f4 x3 = *(const f4*)(hp + kb + 12);
        v[0]=x0.x; v[1]=x0.y; v[2]=x0.z; v[3]=x0.w;
        v[4]=x1.x; v[5]=x1.y; v[6]=x1.z; v[7]=x1.w;
        v[8]=x2.x; v[9]=x2.y; v[10]=x2.z; v[11]=x2.w;
        v[12]=x3.x; v[13]=x3.y; v[14]=x3.z; v[15]=x3.w;
        #pragma unroll
        for (int e = 0; e < 16; ++e) v[e] = fmaxf(v[e] * wv[kb + e], 0.f);
      } else {
        #pragma unroll
        for (int e = 0; e < 16; ++e) {
          int k = kb + e;
          v[e] = (k < 300) ? fmaxf(hp[k] * wv[k], 0.f) : 0.f;
        }
      }
      #pragma unroll
      for (int g4 = 0; g4 < 4; ++g4) {
        int klocal = halfk * 16 + g4 * 4;
        int q = klocal >> 3, wb = klocal & 7;
        int idx = m * 32 + swzq(m, q) * 8 + wb;
        ushort4 hv, lv;
        hv.x = f2bf(v[g4*4+0]); lv.x = f2bf(v[g4*4+0] - bf2f(hv.x));
        hv.y = f2bf(v[g4*4+1]); lv.y = f2bf(v[g4*4+1] - bf2f(hv.y));
        hv.z = f2bf(v[g4*4+2]); lv.z = f2bf(v[g4*4+2] - bf2f(hv.z));
        hv.w = f2bf(v[g4*4+3]); lv.w = f2bf(v[g4*4+3] - bf2f(hv.w));
        *(ushort4*)&Vh[idx] = hv;
        *(ushort4*)&Vl[idx] = lv;
      }
    }
    __syncthreads();
    // wave wid owns output rows half*64 + wid*16 .. +15, all 128 cols
    int ra = half * 64 + wid * 16 + lr;
    int ai = ra * 32 + swzq(ra, lq) * 8;
    s16x8 ah = *(const s16x8*)&Vh[ai];
    s16x8 al = *(const s16x8*)&Vl[ai];
    #pragma unroll
    for (int nf = 0; nf < 8; ++nf) {
      int rb = nf * 16 + lr;
      int bi = rb * 32 + swzq(rb, lq) * 8;
      s16x8 bh = *(const s16x8*)&Vh[bi];
      s16x8 bl = *(const s16x8*)&Vl[bi];
      acc[nf] = mfma4(ah, al, bh, bl, acc[nf]);
    }
  }
  __syncthreads();
  // threshold -> u8 via LDS, then coalesced store
  unsigned char* Au8 = (unsigned char*)Vh;   // 8 KB reuse
  #pragma unroll
  for (int nf = 0; nf < 8; ++nf) {
    int j = nf * 16 + lr;
    #pragma unroll
    for (int t2 = 0; t2 < 4; ++t2) {
      int il = wid * 16 + 4 * lq + t2;
      int i = half * 64 + il;
      Au8[il * 128 + j] = (acc[nf][t2] >= 0.1f || i == j) ? 1 : 0;
    }
  }
  __syncthreads();
  for (int c = tid; c < 512; c += 256) {
    int r = c >> 3, q = c & 7;
    uint4 val = *(const uint4*)&Au8[r * 128 + q * 16];
    *(uint4*)&A[(size_t)(half * 64 + r) * 128 + q * 16] = val;
  }
}

// ---------------- prepW: transpose+split weights into bf16 hi/lo, padded
__global__ __launch_bounds__(256) void prepw_kernel(
    const float* __restrict__ gatW, const float* __restrict__ sageW,
    unsigned short* __restrict__ gWTh, unsigned short* __restrict__ gWTl,
    unsigned short* __restrict__ sWTh, unsigned short* __restrict__ sWTl) {
  int idx = blockIdx.x * 256 + threadIdx.x;
  if (idx < 1280 * 320) {
    int n = idx / 320, k = idx % 320;
    float v = (n < 1200 && k < 300) ? gatW[(size_t)k * 1200 + n] : 0.f;
    unsigned short hv = f2bf(v);
    gWTh[idx] = hv;
    gWTl[idx] = f2bf(v - bf2f(hv));
  } else if (idx < 1280 * 320 + 320 * 320) {
    int i2 = idx - 1280 * 320;
    int n = i2 / 320, k = i2 % 320;
    float v = (n < 300 && k < 300) ? sageW[(size_t)k * 300 + n] : 0.f;
    unsigned short hv = f2bf(v);
    sWTh[i2] = hv;
    sWTl[i2] = f2bf(v - bf2f(hv));
  }
}

// ---------------- zmm: z = h @ gatW via split-bf16 MFMA.
// Writes zT hi/lo coalesced via LDS transpose; fuses el/er (fp32 partials + atomicAdd).
// grid 1280 linear: x=id&7 (XCD), t=id>>3; g=x+8*(t/10), nt=t%10 -> all n-tiles of g on one XCD.
__global__ __launch_bounds__(256) void zmm_mfma(
    const float* __restrict__ h,
    const unsigned short* __restrict__ gWTh, const unsigned short* __restrict__ gWTl,
    const float* __restrict__ attn_l, const float* __restrict__ attn_r,
    unsigned short* __restrict__ zTh, unsigned short* __restrict__ zTl,
    float* __restrict__ el, float* __restrict__ er) {
  __shared__ __align__(16) unsigned short smem[128 * 136];   // 34816 B: staging (32KB) then T[128][136]
  unsigned short* Ah = smem;
  unsigned short* Al = smem + 4096;
  unsigned short* Bh = smem + 8192;
  unsigned short* Bl = smem + 12288;
  int x = blockIdx.x & 7, tb = blockIdx.x >> 3;
  int gi = tb / 10, nt = tb - gi * 10;
  int g = x + 8 * gi;
  int n0 = nt * 128, m0 = g * 128;
  int tid = threadIdx.x, w = tid >> 6, lane = tid & 63;
  int lq = lane >> 4, lr = lane & 15, wr = w >> 1, wc = w & 1;
  f32x4 acc[4][4];
  #pragma unroll
  for (int a = 0; a < 4; ++a)
    #pragma unroll
    for (int b = 0; b < 4; ++b) acc[a][b] = (f32x4){0.f, 0.f, 0.f, 0.f};

  for (int kc = 0; kc < 10; ++kc) {
    // A stage (split from fp32 h)
    {
      int m = tid >> 1, half = tid & 1;
      const float* hp = h + (size_t)(m0 + m) * 300;
      int kb = kc * 32 + half * 16;
      float v[16];
      if (kb + 15 < 300) {
        f4 x0 = *(const f4*)(hp + kb);
        f4 x1 = *(const f4*)(hp + kb + 4);
        f4 x2 = *(const f4*)(hp + kb + 8);
        f4 x3 = *(const f4*)(hp + kb + 12);
        v[0]=x0.x; v[1]=x0.y; v[2]=x0.z; v[3]=x0.w;
        v[4]=x1.x; v[5]=x1.y; v[6]=x1.z; v[7]=x1.w;
        v[8]=x2.x; v[9]=x2.y; v[10]=x2.z; v[11]=x2.w;
        v[12]=x3.x; v[13]=x3.y; v[14]=x3.z; v[15]=x3.w;
      } else {
        #pragma unroll
        for (int e = 0; e < 16; ++e) { int k = kb + e; v[e] = (k < 300) ? hp[k] : 0.f; }
      }
      #pragma unroll
      for (int g4 = 0; g4 < 4; ++g4) {
        int klocal = half * 16 + g4 * 4;
        int q = klocal >> 3, wb = klocal & 7;
        int idx = m * 32 + swzq(m, q) * 8 + wb;
        ushort4 hv, lv;
        hv.x = f2bf(v[g4*4+0]); lv.x = f2bf(v[g4*4+0] - bf2f(hv.x));
        hv.y = f2bf(v[g4*4+1]); lv.y = f2bf(v[g4*4+1] - bf2f(hv.y));
        hv.z = f2bf(v[g4*4+2]); lv.z = f2bf(v[g4*4+2] - bf2f(hv.z));
        hv.w = f2bf(v[g4*4+3]); lv.w = f2bf(v[g4*4+3] - bf2f(hv.w));
        *(ushort4*)&Ah[idx] = hv;
        *(ushort4*)&Al[idx] = lv;
      }
    }
    // B stage (already-split gWT)
    {
      int n = tid >> 1, half = tid & 1;
      const unsigned short* bh = gWTh + (size_t)(n0 + n) * 320 + kc * 32 + half * 16;
      const unsigned short* bl = gWTl + (size_t)(n0 + n) * 320 + kc * 32 + half * 16;
      #pragma unroll
      for (int ff = 0; ff < 2; ++ff) {
        int q = half * 2 + ff;
        int idx = n * 32 + swzq(n, q) * 8;
        *(s16x8*)&Bh[idx] = *(const s16x8*)(bh + ff * 8);
        *(s16x8*)&Bl[idx] = *(const s16x8*)(bl + ff * 8);
      }
    }
    __syncthreads();
    s16x8 ah[4], alo[4];
    #pragma unroll
    for (int mf = 0; mf < 4; ++mf) {
      int row = wr * 64 + mf * 16 + lr;
      int ai = row * 32 + swzq(row, lq) * 8;
      ah[mf] = *(const s16x8*)&Ah[ai];
      alo[mf] = *(const s16x8*)&Al[ai];
    }
    #pragma unroll
    for (int nf = 0; nf < 4; ++nf) {
      int rn = wc * 64 + nf * 16 + lr;
      int bi = rn * 32 + swzq(rn, lq) * 8;
      s16x8 bhv = *(const s16x8*)&Bh[bi];
      s16x8 blv = *(const s16x8*)&Bl[bi];
      #pragma unroll
      for (int mf = 0; mf < 4; ++mf)
        acc[mf][nf] = mfma3(ah[mf], alo[mf], bhv, blv, acc[mf][nf]);
    }
    __syncthreads();
  }

  // ---- fused el/er: fp32 partial dots + atomicAdd (head-boundary split) ----
  {
    int cbase = n0 + wc * 64;
    if (cbase < 1200) {
      int h_base = cbase / 300;
      int h_last = (cbase + 63 < 1200 ? cbase + 63 : 1199) / 300;
      bool has_alt = (h_last != h_base);
      float aLv[4], aRv[4]; int alt[4];
      #pragma unroll
      for (int nf = 0; nf < 4; ++nf) {
        int cg = cbase + nf * 16 + lr;
        bool ok = cg < 1200;
        aLv[nf] = ok ? attn_l[cg] : 0.f;
        aRv[nf] = ok ? attn_r[cg] : 0.f;
        alt[nf] = (ok && (cg / 300) != h_base) ? 1 : 0;
      }
      #pragma unroll
      for (int mf = 0; mf < 4; ++mf) {
        #pragma unroll
        for (int t2 = 0; t2 < 4; ++t2) {
          float s0l = 0.f, s0r = 0.f, s1l = 0.f, s1r = 0.f;
          #pragma unroll
          for (int nf = 0; nf < 4; ++nf) {
            float v = acc[mf][nf][t2];
            float cl = v * aLv[nf], cr = v * aRv[nf];
            s0l += alt[nf] ? 0.f : cl; s1l += alt[nf] ? cl : 0.f;
            s0r += alt[nf] ? 0.f : cr; s1r += alt[nf] ? cr : 0.f;
          }
          #pragma unroll
          for (int mm = 1; mm < 16; mm <<= 1) {
            s0l += __shfl_xor(s0l, mm, 64);
            s0r += __shfl_xor(s0r, mm, 64);
          }
          if (has_alt) {
            #pragma unroll
            for (int mm = 1; mm < 16; mm <<= 1) {
              s1l += __shfl_xor(s1l, mm, 64);
              s1r += __shfl_xor(s1r, mm, 64);
            }
          }
          if (lr == 0) {
            int j = wr * 64 + mf * 16 + 4 * lq + t2;
            atomicAdd(&el[(size_t)(g * 4 + h_base) * 128 + j], s0l);
            atomicAdd(&er[(size_t)(g * 4 + h_base) * 128 + j], s0r);
            if (has_alt) {
              atomicAdd(&el[(size_t)(g * 4 + h_base + 1) * 128 + j], s1l);
              atomicAdd(&er[(size_t)(g * 4 + h_base + 1) * 128 + j], s1r);
            }
          }
        }
      }
    }
  }

  // ---- transposed coalesced zT store: pass 0 = hi, pass 1 = lo ----
  for (int pass = 0; pass < 2; ++pass) {
    __syncthreads();
    #pragma unroll
    for (int mf = 0; mf < 4; ++mf) {
      #pragma unroll
      for (int nf = 0; nf < 4; ++nf) {
        int cl = wc * 64 + nf * 16 + lr;
        int j0 = wr * 64 + mf * 16 + 4 * lq;
        f32x4 a = acc[mf][nf];
        ushort4 pv;
        if (pass == 0) {
          pv.x = f2bf(a[0]); pv.y = f2bf(a[1]); pv.z = f2bf(a[2]); pv.w = f2bf(a[3]);
        } else {
          unsigned short hx;
          hx = f2bf(a[0]); pv.x = f2bf(a[0] - bf2f(hx));
          hx = f2bf(a[1]); pv.y = f2bf(a[1] - bf2f(hx));
          hx = f2bf(a[2]); pv.z = f2bf(a[2] - bf2f(hx));
          hx = f2bf(a[3]); pv.w = f2bf(a[3] - bf2f(hx));
        }
        *(ushort4*)&smem[cl * 136 + j0] = pv;
      }
    }
    __syncthreads();
    unsigned short* dst = pass ? zTl : zTh;
    #pragma unroll
    for (int p = 0; p < 8; ++p) {
      int c = tid + p * 256;            // 0..2047: r = c/16 (c-row), q = chunk of 8 ushorts
      int r = c >> 4, q = c & 15;
      int cg = n0 + r;
      if (cg < 1200) {
        int head = cg / 300, d = cg - head * 300;
        uint4 val = *(const uint4*)&smem[r * 136 + q * 8];
        *(uint4*)(dst + ((size_t)(g * 4 + head) * 300 + d) * 128 + q * 8) = val;
      }
    }
  }
}

// ---------------- alphaP: per-row softmax max & 1/sum; dinv for SAGE
__global__ __launch_bounds__(256) void alphap_kernel(
    const unsigned char* __restrict__ Agat, const unsigned char* __restrict__ Asag,
    const float* __restrict__ el, const float* __restrict__ er,
    float* __restrict__ mx, float* __restrict__ sinv, float* __restrict__ dinv) {
  int g = blockIdx.x, u = blockIdx.y;
  int tid = threadIdx.x, ww = tid >> 6, lane = tid & 63;
  if (u < 4) {
    const float* els = el + (size_t)(g * 4 + u) * 128;
    const float* ers = er + (size_t)(g * 4 + u) * 128;
    float el0 = els[lane], el1 = els[64 + lane];
    for (int i = ww; i < 128; i += 4) {
      const unsigned char* row = Agat + ((size_t)g * 128 + i) * 128;
      int m0 = row[lane], m1 = row[64 + lane];
      float eri = ers[i];
      float e0 = eri + el0; e0 = e0 >= 0.f ? e0 : 0.2f * e0;
      float e1 = eri + el1; e1 = e1 >= 0.f ? e1 : 0.2f * e1;
      float x0 = m0 ? e0 : -3.0e38f;
      float x1 = m1 ? e1 : -3.0e38f;
      float m_ = wmax(fmaxf(x0, x1));
      float p0 = m0 ? __expf(e0 - m_) : 0.f;
      float p1 = m1 ? __expf(e1 - m_) : 0.f;
      float s = wsum(p0 + p1);
      if (lane == 0) {
        mx[(size_t)(g * 4 + u) * 128 + i] = m_;
        sinv[(size_t)(g * 4 + u) * 128 + i] = 1.f / s;
      }
    }
  } else {
    for (int i = ww; i < 128; i += 4) {
      const unsigned char* row = Asag + ((size_t)g * 128 + i) * 128;
      float d = (float)(row[lane] + row[64 + lane]);
      d = wsum(d);
      if (lane == 0) dinv[(size_t)g * 128 + i] = 1.f / (d + 1.f);
    }
  }
}

// ---------------- gat_fuse: 4 GAT heads via MFMA + head weights + residual (XCD-swizzled)
__global__ __launch_bounds__(256) void gat_fuse(
    const float* __restrict__ h, const unsigned char* __restrict__ Agat,
    const unsigned short* __restrict__ zTh, const unsigned short* __restrict__ zTl,
    const float* __restrict__ el, const float* __restrict__ er,
    const float* __restrict__ mx, const float* __restrict__ sinv,
    const float* __restrict__ gat_b, const float* __restrict__ headW,
    const float* __restrict__ head_b, float* __restrict__ out) {
  __shared__ __align__(16) unsigned short Bh[320 * 32], Bl[320 * 32];
  __shared__ __align__(16) unsigned short Ah[32 * 32], Al[32 * 32];
  __shared__ float hwred[2][32];
  __shared__ float wgts[32];
  int xb = blockIdx.x & 7, tb = blockIdx.x >> 3;
  int it = tb & 3, g = xb + 8 * (tb >> 2);
  int i0 = it * 32;
  int tid = threadIdx.x, w = tid >> 6, lane = tid & 63;
  int lq = lane >> 4, lr = lane & 15, wi = w & 1, wn = w >> 1;
  float hb = head_b[0];
  float outacc[10][4];
  #pragma unroll
  for (int nf = 0; nf < 10; ++nf)
    #pragma unroll
    for (int t = 0; t < 4; ++t) outacc[nf][t] = 0.f;

  for (int s = 0; s < 4; ++s) {
    f32x4 acc[10];
    #pragma unroll
    for (int nf = 0; nf < 10; ++nf) acc[nf] = (f32x4){0.f, 0.f, 0.f, 0.f};
    const float* els = el + (size_t)(g * 4 + s) * 128;
    const float* ers = er + (size_t)(g * 4 + s) * 128;
    const float* mxs = mx + (size_t)(g * 4 + s) * 128;
    const unsigned short* zsh = zTh + (size_t)(g * 4 + s) * 300 * 128;
    const unsigned short* zsl = zTl + (size_t)(g * 4 + s) * 300 * 128;

    for (int kc = 0; kc < 4; ++kc) {
      int j0 = kc * 32;
      // A stage: p = mask ? exp(leaky(er_i+el_j) - mx_i) : 0, split hi/lo
      {
        int m = tid >> 3, j4 = (tid & 7) * 4;
        int i = i0 + m;
        float eri = ers[i], mxi = mxs[i];
        const unsigned char* mrow = Agat + ((size_t)g * 128 + i) * 128 + j0 + j4;
        uchar4 msk = *(const uchar4*)mrow;
        f4 elv = *(const f4*)(els + j0 + j4);
        float p[4];
        {
          float e = eri + elv.x; e = e >= 0.f ? e : 0.2f * e; p[0] = msk.x ? __expf(e - mxi) : 0.f;
          e = eri + elv.y; e = e >= 0.f ? e : 0.2f * e; p[1] = msk.y ? __expf(e - mxi) : 0.f;
          e = eri + elv.z; e = e >= 0.f ? e : 0.2f * e; p[2] = msk.z ? __expf(e - mxi) : 0.f;
          e = eri + elv.w; e = e >= 0.f ? e : 0.2f * e; p[3] = msk.w ? __expf(e - mxi) : 0.f;
        }
        int q = j4 >> 3, wb = j4 & 7;
        int idx = m * 32 + swzq(m, q) * 8 + wb;
        ushort4 hv, lv;
        hv.x = f2bf(p[0]); lv.x = f2bf(p[0] - bf2f(hv.x));
        hv.y = f2bf(p[1]); lv.y = f2bf(p[1] - bf2f(hv.y));
        hv.z = f2bf(p[2]); lv.z = f2bf(p[2] - bf2f(hv.z));
        hv.w = f2bf(p[3]); lv.w = f2bf(p[3] - bf2f(hv.w));
        *(ushort4*)&Ah[idx] = hv;
        *(ushort4*)&Al[idx] = lv;
      }
      // B stage: zT rows (d) 0..319, zero for d>=300
      {
        #pragma unroll
        for (int rep = 0; rep < 2; ++rep) {
          int n = rep == 0 ? tid : 256 + tid;
          if (rep == 1 && tid >= 64) break;
          if (n < 300) {
            const unsigned short* src_h = zsh + (size_t)n * 128 + j0;
            const unsigned short* src_l = zsl + (size_t)n * 128 + j0;
            #pragma unroll
            for (int q = 0; q < 4; ++q) {
              int idx = n * 32 + swzq(n, q) * 8;
              *(s16x8*)&Bh[idx] = *(const s16x8*)(src_h + q * 8);
              *(s16x8*)&Bl[idx] = *(const s16x8*)(src_l + q * 8);
            }
          } else {
            s16x8 z8 = (s16x8){0,0,0,0,0,0,0,0};
            #pragma unroll
            for (int q = 0; q < 4; ++q) {
              int idx = n * 32 + swzq(n, q) * 8;
              *(s16x8*)&Bh[idx] = z8;
              *(s16x8*)&Bl[idx] = z8;
            }
          }
        }
      }
      __syncthreads();
      int rowa = wi * 16 + lr;
      int ai = rowa * 32 + swzq(rowa, lq) * 8;
      s16x8 ah = *(const s16x8*)&Ah[ai];
      s16x8 alv = *(const s16x8*)&Al[ai];
      #pragma unroll
      for (int nf = 0; nf < 10; ++nf) {
        int rn = wn * 160 + nf * 16 + lr;
        int bi = rn * 32 + swzq(rn, lq) * 8;
        s16x8 bhv = *(const s16x8*)&Bh[bi];
        s16x8 blv = *(const s16x8*)&Bl[bi];
        acc[nf] = mfma3(ah, alv, bhv, blv, acc[nf]);
      }
      __syncthreads();
    }
    // epilogue for slot s
    f4 sv4 = *(const f4*)(sinv + (size_t)(g * 4 + s) * 128 + i0 + wi * 16 + 4 * lq);
    float svf[4] = {sv4.x, sv4.y, sv4.z, sv4.w};
    float pt[4] = {0.f, 0.f, 0.f, 0.f};
    #pragma unroll
    for (int nf = 0; nf < 10; ++nf) {
      int c = wn * 160 + nf * 16 + lr;
      bool val = c < 300;
      float gb = val ? gat_b[s * 300 + c] : 0.f;
      float hwv = val ? headW[c] : 0.f;
      #pragma unroll
      for (int t = 0; t < 4; ++t) {
        float gvv = acc[nf][t] * svf[t] + gb;
        acc[nf][t] = gvv;
        pt[t] += gvv * hwv;
      }
    }
    #pragma unroll
    for (int t = 0; t < 4; ++t) {
      #pragma unroll
      for (int mm = 1; mm < 16; mm <<= 1) pt[t] += __shfl_xor(pt[t], mm, 64);
    }
    if (lr == 0) {
      #pragma unroll
      for (int t = 0; t < 4; ++t) hwred[wn][wi * 16 + 4 * lq + t] = pt[t];
    }
    __syncthreads();
    if (tid < 32) wgts[tid] = sigm(hwred[0][tid] + hwred[1][tid] + hb);
    __syncthreads();
    #pragma unroll
    for (int nf = 0; nf < 10; ++nf) {
      #pragma unroll
      for (int t = 0; t < 4; ++t) {
        int r = wi * 16 + 4 * lq + t;
        outacc[nf][t] += wgts[r] * acc[nf][t];
      }
    }
    __syncthreads();
  }
  // final: out = h + sum of weighted gat heads (sage added later)
  #pragma unroll
  for (int nf = 0; nf < 10; ++nf) {
    int c = wn * 160 + nf * 16 + lr;
    if (c < 300) {
      #pragma unroll
      for (int t = 0; t < 4; ++t) {
        int r = wi * 16 + 4 * lq + t;
        size_t o = ((size_t)(g * 128 + i0 + r)) * 300 + c;
        out[o] = h[o] + outacc[nf][t];
      }
    }
  }
}

// ---------------- neigh (fp32): n = (Asag@h + h)*dinv -> split bf16 (XCD-swizzled)
__global__ __launch_bounds__(256) void neigh_kernel(
    const float* __restrict__ h, const unsigned char* __restrict__ Asag,
    const float* __restrict__ dinv,
    unsigned short* __restrict__ nh, unsigned short* __restrict__ nl) {
  __shared__ float As[16][128];
  int g, it; xcd_decode8(blockIdx.x, g, it);
  int i0 = it * 16;
  int tid = threadIdx.x, ii = tid >> 6, lane = tid & 63;
  for (int idx = tid; idx < 16 * 128; idx += 256)
    As[idx >> 7][idx & 127] = (float)Asag[((size_t)g * 128 + i0 + (idx >> 7)) * 128 + (idx & 127)];
  __syncthreads();
  int dq0 = lane, dq1 = lane + 64;
  bool ok1 = dq1 < 75;
  const f4 zero4 = make_float4(0.f, 0.f, 0.f, 0.f);
  const f4* h4 = (const f4*)(h + (size_t)g * LLN * DDIM);
  f4 acc0[4], acc1[4];
  #pragma unroll
  for (int r = 0; r < 4; ++r) { acc0[r] = zero4; acc1[r] = zero4; }
  for (int j = 0; j < 128; ++j) {
    float a0 = As[ii*4+0][j], a1 = As[ii*4+1][j], a2 = As[ii*4+2][j], a3 = As[ii*4+3][j];
    f4 hv0 = h4[j * 75 + dq0];
    f4 hv1 = ok1 ? h4[j * 75 + dq1] : zero4;
    FMA4(acc0[0], hv0, a0); FMA4(acc0[1], hv0, a1); FMA4(acc0[2], hv0, a2); FMA4(acc0[3], hv0, a3);
    FMA4(acc1[0], hv1, a0); FMA4(acc1[1], hv1, a1); FMA4(acc1[2], hv1, a2); FMA4(acc1[3], hv1, a3);
  }
  #pragma unroll
  for (int r = 0; r < 4; ++r) {
    int i = i0 + ii * 4 + r;
    float dv = dinv[(size_t)g * 128 + i];
    f4 n0v = scale4(add4(acc0[r], h4[i * 75 + dq0]), dv);
    size_t base = (size_t)(g * 128 + i) * 320;
    ushort4 hv, lv;
    hv.x = f2bf(n0v.x); lv.x = f2bf(n0v.x - bf2f(hv.x));
    hv.y = f2bf(n0v.y); lv.y = f2bf(n0v.y - bf2f(hv.y));
    hv.z = f2bf(n0v.z); lv.z = f2bf(n0v.z - bf2f(hv.z));
    hv.w = f2bf(n0v.w); lv.w = f2bf(n0v.w - bf2f(hv.w));
    *(ushort4*)&nh[base + dq0 * 4] = hv;
    *(ushort4*)&nl[base + dq0 * 4] = lv;
    if (ok1) {
      f4 n1v = scale4(add4(acc1[r], h4[i * 75 + dq1]), dv);
      hv.x = f2bf(n1v.x); lv.x = f2bf(n1v.x - bf2f(hv.x));
      hv.y = f2bf(n1v.y); lv.y = f2bf(n1v.y - bf2f(hv.y));
      hv.z = f2bf(n1v.z); lv.z = f2bf(n1v.z - bf2f(hv.z));
      hv.w = f2bf(n1v.w); lv.w = f2bf(n1v.w - bf2f(hv.w));
      *(ushort4*)&nh[base + dq1 * 4] = hv;
      *(ushort4*)&nl[base + dq1 * 4] = lv;
    }
    if (lane < 5) {
      ushort4 z4u = {0, 0, 0, 0};
      *(ushort4*)&nh[base + 300 + lane * 4] = z4u;
      *(ushort4*)&nl[base + 300 + lane * 4] = z4u;
    }
  }
}

// ---------------- sage_fuse: sage = neigh@sageW + b; out += sigmoid(dot)*sage
__global__ __launch_bounds__(256) void sage_fuse(
    const unsigned short* __restrict__ nh, const unsigned short* __restrict__ nl,
    const unsigned short* __restrict__ sWTh, const unsigned short* __restrict__ sWTl,
    const float* __restrict__ sage_b, const float* __restrict__ headW,
    const float* __restrict__ head_b, float* __restrict__ out) {
  __shared__ __align__(16) unsigned short Bh[320 * 32], Bl[320 * 32];
  __shared__ __align__(16) unsigned short Ah[32 * 32], Al[32 * 32];
  __shared__ float hwred[2][32];
  __shared__ float wgts[32];
  int m0 = blockIdx.x * 32;
  int tid = threadIdx.x, w = tid >> 6, lane = tid & 63;
  int lq = lane >> 4, lr = lane & 15, wi = w & 1, wn = w >> 1;
  float hb = head_b[0];
  f32x4 acc[10];
  #pragma unroll
  for (int nf = 0; nf < 10; ++nf) acc[nf] = (f32x4){0.f, 0.f, 0.f, 0.f};

  for (int kc = 0; kc < 10; ++kc) {
    {
      int t = tid & 127;
      int rowm = t >> 2, qq = t & 3;
      int idx = rowm * 32 + swzq(rowm, qq) * 8;
      if (tid < 128) {
        const unsigned short* src = nh + (size_t)(m0 + rowm) * 320 + kc * 32 + qq * 8;
        *(s16x8*)&Ah[idx] = *(const s16x8*)src;
      } else {
        const unsigned short* src = nl + (size_t)(m0 + rowm) * 320 + kc * 32 + qq * 8;
        *(s16x8*)&Al[idx] = *(const s16x8*)src;
      }
    }
    {
      #pragma unroll
      for (int rep = 0; rep < 2; ++rep) {
        int n = rep == 0 ? tid : 256 + tid;
        if (rep == 1 && tid >= 64) break;
        const unsigned short* src_h = sWTh + (size_t)n * 320 + kc * 32;
        const unsigned short* src_l = sWTl + (size_t)n * 320 + kc * 32;
        #pragma unroll
        for (int q = 0; q < 4; ++q) {
          int idx = n * 32 + swzq(n, q) * 8;
          *(s16x8*)&Bh[idx] = *(const s16x8*)(src_h + q * 8);
          *(s16x8*)&Bl[idx] = *(const s16x8*)(src_l + q * 8);
        }
      }
    }
    __syncthreads();
    int rowa = wi * 16 + lr;
    int ai = rowa * 32 + swzq(rowa, lq) * 8;
    s16x8 ah = *(const s16x8*)&Ah[ai];
    s16x8 alv = *(const s16x8*)&Al[ai];
    #pragma unroll
    for (int nf = 0; nf < 10; ++nf) {
      int rn = wn * 160 + nf * 16 + lr;
      int bi = rn * 32 + swzq(rn, lq) * 8;
      s16x8 bhv = *(const s16x8*)&Bh[bi];
      s16x8 blv = *(const s16x8*)&Bl[bi];
      acc[nf] = mfma3(ah, alv, bhv, blv, acc[nf]);
    }
    __syncthreads();
  }
  float pt[4] = {0.f, 0.f, 0.f, 0.f};
  #pragma unroll
  for (int nf = 0; nf < 10; ++nf) {
    int c = wn * 160 + nf * 16 + lr;
    bool val = c < 300;
    float sb = val ? sage_b[c] : 0.f;
    float hwv = val ? headW[c] : 0.f;
    #pragma unroll
    for (int t = 0; t < 4; ++t) {
      float gvv = acc[nf][t] + sb;
      acc[nf][t] = gvv;
      pt[t] += gvv * hwv;
    }
  }
  #pragma unroll
  for (int t = 0; t < 4; ++t) {
    #pragma unroll
    for (int mm = 1; mm < 16; mm <<= 1) pt[t] += __shfl_xor(pt[t], mm, 64);
  }
  if (lr == 0) {
    #pragma unroll
    for (int t = 0; t < 4; ++t) hwred[wn][wi * 16 + 4 * lq + t] = pt[t];
  }
  __syncthreads();
  if (tid < 32) wgts[tid] = sigm(hwred[0][tid] + hwred[1][tid] + hb);
  __syncthreads();
  #pragma unroll
  for (int nf = 0; nf < 10; ++nf) {
    int c = wn * 160 + nf * 16 + lr;
    if (c < 300) {
      #pragma unroll
      for (int t = 0; t < 4; ++t) {
        int r = wi * 16 + 4 * lq + t;
        size_t o = ((size_t)(m0 + r)) * 300 + c;
        out[o] = out[o] + wgts[r] * acc[nf][t];
      }
    }
  }
}

// ---------------- WeightAndSum pool
__global__ __launch_bounds__(256) void pool_kernel(
    const float* __restrict__ h, const float* __restrict__ poolW,
    const float* __restrict__ pool_b, float* __restrict__ gvec) {
  __shared__ float ws_[128];
  int g = blockIdx.x, tid = threadIdx.x, ii = tid >> 6, lane = tid & 63;
  const float* hg = h + (size_t)g * LLN * DDIM;
  float pb = pool_b[0];
  for (int m = 0; m < 32; ++m) {
    int l = ii * 32 + m;
    float p = 0.f;
    for (int d = lane; d < DDIM; d += 64) p += hg[l * DDIM + d] * poolW[d];
    p = wsum(p);
    if (lane == 0) ws_[l] = 1.f / (1.f + __expf(-(p + pb)));
  }
  __syncthreads();
  for (int d = tid; d < DDIM; d += 256) {
    float acc = 0.f;
    for (int l = 0; l < 128; ++l) acc += hg[l * DDIM + d] * ws_[l];
    gvec[(size_t)g * DDIM + d] = acc;
  }
}

// ---------------- pearson
__global__ __launch_bounds__(64) void pearson_kernel(
    const float* __restrict__ gvec, float* __restrict__ out) {
  int b = blockIdx.x, lane = threadIdx.x;
  const float* g1 = gvec + (size_t)b * DDIM;
  const float* g2 = gvec + (size_t)(64 + b) * DDIM;
  float v1[5], v2[5];
  float s1 = 0.f, s2 = 0.f;
  #pragma unroll
  for (int q = 0; q < 5; ++q) {
    int d = lane + 64 * q;
    v1[q] = (d < DDIM) ? g1[d] : 0.f;
    v2[q] = (d < DDIM) ? g2[d] : 0.f;
    s1 += v1[q]; s2 += v2[q];
  }
  s1 = wsum(s1); s2 = wsum(s2);
  float m1 = s1 / 300.f, m2 = s2 / 300.f;
  float a = 0.f, bb = 0.f, c = 0.f;
  #pragma unroll
  for (int q = 0; q < 5; ++q) {
    int d = lane + 64 * q;
    if (d < DDIM) {
      float x = v1[q] - m1, y = v2[q] - m2;
      a += x * y; bb += x * x; c += y * y;
    }
  }
  a = wsum(a); bb = wsum(bb); c = wsum(c);
  if (lane == 0) out[b] = 5.f * a / (sqrtf(bb) * sqrtf(c));
}

extern "C" void kernel_launch(void* const* d_in, const int* in_sizes, int n_in,
                              void* d_out, int out_size, void* d_ws, size_t ws_size,
                              hipStream_t stream) {
  (void)in_sizes; (void)n_in; (void)out_size; (void)ws_size;
  const float* emb   = (const float*)d_in[0];
  const float* simw1 = (const float*)d_in[1];
  const float* simw2 = (const float*)d_in[2];
  const float* LP[2][8];
  for (int l = 0; l < 2; ++l)
    for (int p = 0; p < 8; ++p) LP[l][p] = (const float*)d_in[3 + l * 8 + p];
  const float* poolW  = (const float*)d_in[19];
  const float* pool_b = (const float*)d_in[20];
  const int* s1 = (const int*)d_in[21];
  const int* s2 = (const int*)d_in[22];
  float* out = (float*)d_out;

  char* ws = (char*)d_ws;
  float* hA  = (float*)(ws + 0);                         // 19,660,800
  float* hB  = (float*)(ws + 19660800);                  // 19,660,800
  unsigned short* zTh = (unsigned short*)(ws + 39321600);   // 39,321,600
  unsigned short* zTl = (unsigned short*)(ws + 78643200);   // 39,321,600
  unsigned short* nh = (unsigned short*)(ws + 39321600); // alias zTh (post-gat_fuse)
  unsigned short* nl = (unsigned short*)(ws + 78643200); // alias zTl
  unsigned char* Agat = (unsigned char*)(ws + 117964800); // 2,097,152
  unsigned char* Asag = (unsigned char*)(ws + 120061952); // 2,097,152
  float* elb  = (float*)(ws + 122159104);                // 262,144
  float* erb  = (float*)(ws + 122421248);                // 262,144 (contiguous with elb)
  float* mxb  = (float*)(ws + 122683392);                // 262,144
  float* sinvb= (float*)(ws + 122945536);                // 262,144
  float* dinvb= (float*)(ws + 123207680);                // 65,536
  unsigned short* gWTh = (unsigned short*)(ws + 123273216); // 819,200
  unsigned short* gWTl = (unsigned short*)(ws + 124092416); // 819,200
  unsigned short* sWTh = (unsigned short*)(ws + 124911616); // 204,800
  unsigned short* sWTl = (unsigned short*)(ws + 125116416); // 204,800
  float* gv   = (float*)(ws + 125321216);                // 153,600

  gather_kernel<<<GG * LLN, 256, 0, stream>>>(emb, s1, s2, hA);

  float* hin = hA; float* hout = hB;
  for (int l = 0; l < 2; ++l) {
    adjmm_kernel<<<512, 256, 0, stream>>>(hin, simw1, simw2, Agat, Asag);
    prepw_kernel<<<2000, 256, 0, stream>>>(LP[l][0], LP[l][4], gWTh, gWTl, sWTh, sWTl);
    hipMemsetAsync(elb, 0, 524288, stream);   // zero el+er (contiguous)
    zmm_mfma<<<1280, 256, 0, stream>>>(hin, gWTh, gWTl, LP[l][1], LP[l][2],
                                       zTh, zTl, elb, erb);
    alphap_kernel<<<dim3(GG, 5), 256, 0, stream>>>(Agat, Asag, elb, erb, mxb, sinvb, dinvb);
    gat_fuse<<<512, 256, 0, stream>>>(hin, Agat, zTh, zTl, elb, erb, mxb, sinvb,
        LP[l][3], LP[l][6], LP[l][7], hout);
    neigh_kernel<<<1024, 256, 0, stream>>>(hin, Asag, dinvb, nh, nl);
    sage_fuse<<<512, 256, 0, stream>>>(nh, nl, sWTh, sWTl, LP[l][5], LP[l][6], LP[l][7], hout);
    float* t = hin; hin = hout; hout = t;
  }

  pool_kernel<<<GG, 256, 0, stream>>>(hin, poolW, pool_b, gv);
  pearson_kernel<<<64, 64, 0, stream>>>(gv, out);
}